// Round 1
// baseline (1386.927 us; speedup 1.0000x reference)
//
#include <hip/hip_runtime.h>
#include <math.h>

#define NN    4096
#define CIN   128
#define CO    128
#define HD    512
#define KK    20
#define EE    21
#define EDGES (NN * EE)   // 86016
#define LNEPS 1e-5f

typedef unsigned short u16;
typedef unsigned int   u32;
typedef unsigned long long u64;

__device__ __forceinline__ u16 f2b(float x) {
    u32 u = __float_as_uint(x);
    u32 r = u + 0x7fffu + ((u >> 16) & 1u);   // round-to-nearest-even
    return (u16)(r >> 16);
}
__device__ __forceinline__ float b2f(u16 h) {
    return __uint_as_float(((u32)h) << 16);
}

// ---------------- kNN: 1 wave per node ----------------
__global__ __launch_bounds__(64) void k_knn(const float* __restrict__ pos,
                                            int* __restrict__ idxg)
{
    int i = blockIdx.x;
    int lane = threadIdx.x;
    float px = pos[3*i], py = pos[3*i+1], pz = pos[3*i+2];
    float bd[KK]; int bi[KK];
#pragma unroll
    for (int s = 0; s < KK; ++s) { bd[s] = INFINITY; bi[s] = 0x7fffffff; }
    for (int j = lane; j < NN; j += 64) {
        float dx = px - pos[3*j], dy = py - pos[3*j+1], dz = pz - pos[3*j+2];
        float d2 = dx*dx + dy*dy + dz*dz;
        if (j != i && d2 < bd[KK-1]) {
            float cd = d2; int ci = j;
#pragma unroll
            for (int s = 0; s < KK; ++s) {   // static-index bubble insert
                bool sw = cd < bd[s];
                float td = sw ? bd[s] : cd;  int ti = sw ? bi[s] : ci;
                bd[s] = sw ? cd : bd[s];     bi[s] = sw ? ci : bi[s];
                cd = td; ci = ti;
            }
        }
    }
    // extract global 20 smallest via packed u64 wave-min rounds
    for (int r = 0; r < KK; ++r) {
        u64 m = ~0ull;
#pragma unroll
        for (int s = 0; s < KK; ++s) {
            u64 k = ((u64)__float_as_uint(bd[s]) << 32) | (u32)bi[s];
            m = k < m ? k : m;
        }
#pragma unroll
        for (int off = 32; off > 0; off >>= 1) {
            u64 o = __shfl_xor(m, off, 64);
            m = o < m ? o : m;
        }
        if (lane == 0) idxg[i*EE + r] = (int)(u32)m;
#pragma unroll
        for (int s = 0; s < KK; ++s) {
            u64 k = ((u64)__float_as_uint(bd[s]) << 32) | (u32)bi[s];
            if (k == m) bd[s] = INFINITY;
        }
    }
    if (lane == 0) idxg[i*EE + KK] = i;   // self-loop appended
}

// ---------------- v / a_src / a_dst ----------------
__global__ __launch_bounds__(256) void k_lin3(const float* __restrict__ x,
        const float* __restrict__ Wl, const float* __restrict__ Ws, const float* __restrict__ Wd,
        float* __restrict__ v, float* __restrict__ as_, float* __restrict__ ad)
{
    __shared__ float sx[8][CIN];
    int b = blockIdx.x, t = threadIdx.x;
    int n0 = b * 8;
    for (int q = t; q < 8*CIN; q += 256) sx[q >> 7][q & 127] = x[n0*CIN + q];
    __syncthreads();
    int c = t & 127, g = t >> 7;
    float al[4] = {0,0,0,0}, asr[4] = {0,0,0,0}, adr[4] = {0,0,0,0};
    for (int k = 0; k < CIN; ++k) {
        float wl = Wl[k*CO + c], ws = Ws[k*CO + c], wd = Wd[k*CO + c];
#pragma unroll
        for (int nn2 = 0; nn2 < 4; ++nn2) {
            float xv = sx[g*4 + nn2][k];
            al[nn2]  = fmaf(xv, wl, al[nn2]);
            asr[nn2] = fmaf(xv, ws, asr[nn2]);
            adr[nn2] = fmaf(xv, wd, adr[nn2]);
        }
    }
#pragma unroll
    for (int nn2 = 0; nn2 < 4; ++nn2) {
        int n = n0 + g*4 + nn2;
        v[n*CO + c]   = al[nn2];
        as_[n*CO + c] = asr[nn2];
        ad[n*CO + c]  = adr[nn2];
    }
}

// ---------------- LayerNorm + ELU helpers (rows in LDS) ----------------
template<int L>
__device__ __forceinline__ void ln_elu_b16(u16* base, int rows,
        const float* __restrict__ gam, const float* __restrict__ bet)
{
    int t = threadIdx.x, lane = t & 63, w = t >> 6;
    constexpr int P = L / 64;
    for (int e = w; e < rows; e += 4) {
        u16* row = base + e * L;
        float vals[P]; float s = 0.f, sq = 0.f;
#pragma unroll
        for (int q = 0; q < P; ++q) {
            float xx = b2f(row[lane + q*64]);
            vals[q] = xx; s += xx; sq += xx*xx;
        }
#pragma unroll
        for (int off = 32; off > 0; off >>= 1) {
            s  += __shfl_xor(s,  off, 64);
            sq += __shfl_xor(sq, off, 64);
        }
        float mn = s * (1.0f / L);
        float var = sq * (1.0f / L) - mn*mn;
        float rstd = rsqrtf(var + LNEPS);
#pragma unroll
        for (int q = 0; q < P; ++q) {
            int cc = lane + q*64;
            float y = (vals[q] - mn) * rstd * gam[cc] + bet[cc];
            y = y > 0.f ? y : expm1f(y);
            row[cc] = f2b(y);
        }
    }
}

template<int L>
__device__ __forceinline__ void ln_elu_f32(float* base, int rows,
        const float* __restrict__ gam, const float* __restrict__ bet)
{
    int t = threadIdx.x, lane = t & 63, w = t >> 6;
    constexpr int P = L / 64;
    for (int e = w; e < rows; e += 4) {
        float* row = base + e * L;
        float vals[P]; float s = 0.f, sq = 0.f;
#pragma unroll
        for (int q = 0; q < P; ++q) {
            float xx = row[lane + q*64];
            vals[q] = xx; s += xx; sq += xx*xx;
        }
#pragma unroll
        for (int off = 32; off > 0; off >>= 1) {
            s  += __shfl_xor(s,  off, 64);
            sq += __shfl_xor(sq, off, 64);
        }
        float mn = s * (1.0f / L);
        float var = sq * (1.0f / L) - mn*mn;
        float rstd = rsqrtf(var + LNEPS);
#pragma unroll
        for (int q = 0; q < P; ++q) {
            int cc = lane + q*64;
            float y = (vals[q] - mn) * rstd * gam[cc] + bet[cc];
            y = y > 0.f ? y : expm1f(y);
            row[cc] = y;
        }
    }
}

// ---------------- pos_nn: rel -> h(512) -> LN/ELU -> delta(128) -> LN/ELU ----------------
__global__ __launch_bounds__(256) void k_posnn(
        const float* __restrict__ pos, const int* __restrict__ idxg,
        const float* __restrict__ pw1, const float* __restrict__ pb1,
        const float* __restrict__ pg1, const float* __restrict__ pbt1,
        const float* __restrict__ pw2, const float* __restrict__ pb2,
        const float* __restrict__ pg2, const float* __restrict__ pbt2,
        u16* __restrict__ delta)
{
    __shared__ u16   s_h[32][HD];     // 32 KB, bf16 hidden
    __shared__ float s_d[32][CO];     // 16 KB
    __shared__ float s_w[32*CO];      // 16 KB weight stage
    __shared__ float s_rel[32][3];
    int t = threadIdx.x;
    int e0g = blockIdx.x * 32;        // 86016 / 32 = 2688 exact
    if (t < 32) {
        int e = e0g + t;
        u32 ii = (u32)e / 21u;
        int j = idxg[e];
        s_rel[t][0] = pos[3*ii]   - pos[3*j];
        s_rel[t][1] = pos[3*ii+1] - pos[3*j+1];
        s_rel[t][2] = pos[3*ii+2] - pos[3*j+2];
    }
    __syncthreads();
    {   // layer P1: h = rel @ pw1 + pb1 (each thread: 2 channels, all 32 rows)
        int c1 = t, c2 = t + 256;
        float wa0 = pw1[c1], wa1 = pw1[HD + c1], wa2 = pw1[2*HD + c1], ba = pb1[c1];
        float wb0 = pw1[c2], wb1 = pw1[HD + c2], wb2 = pw1[2*HD + c2], bb = pb1[c2];
        for (int r = 0; r < 32; ++r) {
            float r0 = s_rel[r][0], r1 = s_rel[r][1], r2 = s_rel[r][2];
            s_h[r][c1] = f2b(ba + r0*wa0 + r1*wa1 + r2*wa2);
            s_h[r][c2] = f2b(bb + r0*wb0 + r1*wb1 + r2*wb2);
        }
    }
    __syncthreads();
    ln_elu_b16<HD>(&s_h[0][0], 32, pg1, pbt1);
    __syncthreads();
    // layer P2: delta = h @ pw2 + pb2 ; thread tile: 4 edges x 4 cols
    int cq = t & 31, c0 = 4*cq, eg = t >> 5, e0 = eg*4;
    float acc[4][4];
#pragma unroll
    for (int a = 0; a < 4; ++a)
#pragma unroll
        for (int b = 0; b < 4; ++b) acc[a][b] = 0.f;
    for (int kc = 0; kc < HD; kc += 32) {
        __syncthreads();
        for (int q = t*4; q < 32*CO; q += 1024)
            *(float4*)&s_w[q] = *(const float4*)&pw2[kc*CO + q];
        __syncthreads();
        for (int k0 = 0; k0 < 32; k0 += 4) {
            float4 w0 = *(const float4*)&s_w[(k0+0)*CO + c0];
            float4 w1 = *(const float4*)&s_w[(k0+1)*CO + c0];
            float4 w2 = *(const float4*)&s_w[(k0+2)*CO + c0];
            float4 w3 = *(const float4*)&s_w[(k0+3)*CO + c0];
#pragma unroll
            for (int ee = 0; ee < 4; ++ee) {
                ushort4 hu = *(const ushort4*)&s_h[e0+ee][kc + k0];
                float h0 = b2f(hu.x), h1 = b2f(hu.y), h2 = b2f(hu.z), h3 = b2f(hu.w);
                acc[ee][0] = fmaf(h3, w3.x, fmaf(h2, w2.x, fmaf(h1, w1.x, fmaf(h0, w0.x, acc[ee][0]))));
                acc[ee][1] = fmaf(h3, w3.y, fmaf(h2, w2.y, fmaf(h1, w1.y, fmaf(h0, w0.y, acc[ee][1]))));
                acc[ee][2] = fmaf(h3, w3.z, fmaf(h2, w2.z, fmaf(h1, w1.z, fmaf(h0, w0.z, acc[ee][2]))));
                acc[ee][3] = fmaf(h3, w3.w, fmaf(h2, w2.w, fmaf(h1, w1.w, fmaf(h0, w0.w, acc[ee][3]))));
            }
        }
    }
    __syncthreads();
#pragma unroll
    for (int ee = 0; ee < 4; ++ee)
#pragma unroll
        for (int ccc = 0; ccc < 4; ++ccc)
            s_d[e0+ee][c0+ccc] = acc[ee][ccc] + pb2[c0+ccc];
    __syncthreads();
    ln_elu_f32<CO>(&s_d[0][0], 32, pg2, pbt2);
    __syncthreads();
    for (int q = t; q < 32*CO; q += 256)
        delta[(size_t)e0g*CO + q] = f2b(s_d[q >> 7][q & 127]);
}

// ---------------- attn_nn + softmax + aggregate, per node ----------------
__global__ __launch_bounds__(256) void k_attn(
        const int* __restrict__ idxg,
        const float* __restrict__ v, const float* __restrict__ as_, const float* __restrict__ ad,
        const u16* __restrict__ delta,
        const float* __restrict__ aw1, const float* __restrict__ ab1,
        const float* __restrict__ ag1, const float* __restrict__ abt1,
        const float* __restrict__ aw2, const float* __restrict__ ab2,
        const float* __restrict__ ag2, const float* __restrict__ abt2,
        float* __restrict__ out)
{
    __shared__ u16   s_a[24][CO];     // alpha0 bf16, rows 21..23 zero
    __shared__ u16   s_h2[24][HD];    // 24 KB
    __shared__ float s_af[24][CO];    // 12 KB
    __shared__ float s_w[16*HD];      // 32 KB weight stage (A1 full, A2 first 4096)
    __shared__ int   s_idx[EE];
    int i = blockIdx.x, t = threadIdx.x;
    if (t < EE) s_idx[t] = idxg[i*EE + t];
    __syncthreads();
    {   // alpha0 = a_dst[i] - a_src[j] + delta
        int c = t & 127, g = t >> 7;
        float adv = ad[i*CO + c];
        for (int e = g; e < 24; e += 2) {
            float val = 0.f;
            if (e < EE) {
                int j = s_idx[e];
                val = adv - as_[j*CO + c] + b2f(delta[(size_t)(i*EE + e)*CO + c]);
            }
            s_a[e][c] = f2b(val);
        }
    }
    __syncthreads();
    {   // A1: h2 = alpha0 @ aw1 + ab1 ; [24,128]@[128,512]; thread: 12 edges x 4 cols
        int cq = t & 127, c0 = 4*cq, eg = t >> 7, e0 = eg*12;
        float acc[12][4];
#pragma unroll
        for (int a = 0; a < 12; ++a)
#pragma unroll
            for (int b = 0; b < 4; ++b) acc[a][b] = 0.f;
        for (int kc = 0; kc < CIN; kc += 16) {
            __syncthreads();
            for (int q = t*4; q < 16*HD; q += 1024)
                *(float4*)&s_w[q] = *(const float4*)&aw1[kc*HD + q];
            __syncthreads();
            for (int k0 = 0; k0 < 16; k0 += 4) {
                float4 w0 = *(const float4*)&s_w[(k0+0)*HD + c0];
                float4 w1 = *(const float4*)&s_w[(k0+1)*HD + c0];
                float4 w2 = *(const float4*)&s_w[(k0+2)*HD + c0];
                float4 w3 = *(const float4*)&s_w[(k0+3)*HD + c0];
#pragma unroll
                for (int ee = 0; ee < 12; ++ee) {
                    ushort4 hu = *(const ushort4*)&s_a[e0+ee][kc + k0];
                    float h0 = b2f(hu.x), h1 = b2f(hu.y), h2 = b2f(hu.z), h3 = b2f(hu.w);
                    acc[ee][0] = fmaf(h3, w3.x, fmaf(h2, w2.x, fmaf(h1, w1.x, fmaf(h0, w0.x, acc[ee][0]))));
                    acc[ee][1] = fmaf(h3, w3.y, fmaf(h2, w2.y, fmaf(h1, w1.y, fmaf(h0, w0.y, acc[ee][1]))));
                    acc[ee][2] = fmaf(h3, w3.z, fmaf(h2, w2.z, fmaf(h1, w1.z, fmaf(h0, w0.z, acc[ee][2]))));
                    acc[ee][3] = fmaf(h3, w3.w, fmaf(h2, w2.w, fmaf(h1, w1.w, fmaf(h0, w0.w, acc[ee][3]))));
                }
            }
        }
#pragma unroll
        for (int ee = 0; ee < 12; ++ee) {
            int e = e0 + ee;
            if (e < EE) {
#pragma unroll
                for (int ccc = 0; ccc < 4; ++ccc)
                    s_h2[e][c0+ccc] = f2b(acc[ee][ccc] + ab1[c0+ccc]);
            }
        }
    }
    for (int q = t; q < 3*HD; q += 256) s_h2[EE + q/HD][q % HD] = 0;  // zero pad rows
    __syncthreads();
    ln_elu_b16<HD>(&s_h2[0][0], EE, ag1, abt1);
    __syncthreads();
    {   // A2: alphaF = h2 @ aw2 + ab2 ; [24,512]@[512,128]; thread: 3 edges x 4 cols
        int cq = t & 31, c0 = 4*cq, eg = t >> 5, e0 = eg*3;
        float acc[3][4];
#pragma unroll
        for (int a = 0; a < 3; ++a)
#pragma unroll
            for (int b = 0; b < 4; ++b) acc[a][b] = 0.f;
        for (int kc = 0; kc < HD; kc += 32) {
            __syncthreads();
            for (int q = t*4; q < 32*CO; q += 1024)
                *(float4*)&s_w[q] = *(const float4*)&aw2[kc*CO + q];
            __syncthreads();
            for (int k0 = 0; k0 < 32; k0 += 4) {
                float4 w0 = *(const float4*)&s_w[(k0+0)*CO + c0];
                float4 w1 = *(const float4*)&s_w[(k0+1)*CO + c0];
                float4 w2 = *(const float4*)&s_w[(k0+2)*CO + c0];
                float4 w3 = *(const float4*)&s_w[(k0+3)*CO + c0];
#pragma unroll
                for (int ee = 0; ee < 3; ++ee) {
                    ushort4 hu = *(const ushort4*)&s_h2[e0+ee][kc + k0];
                    float h0 = b2f(hu.x), h1 = b2f(hu.y), h2 = b2f(hu.z), h3 = b2f(hu.w);
                    acc[ee][0] = fmaf(h3, w3.x, fmaf(h2, w2.x, fmaf(h1, w1.x, fmaf(h0, w0.x, acc[ee][0]))));
                    acc[ee][1] = fmaf(h3, w3.y, fmaf(h2, w2.y, fmaf(h1, w1.y, fmaf(h0, w0.y, acc[ee][1]))));
                    acc[ee][2] = fmaf(h3, w3.z, fmaf(h2, w2.z, fmaf(h1, w1.z, fmaf(h0, w0.z, acc[ee][2]))));
                    acc[ee][3] = fmaf(h3, w3.w, fmaf(h2, w2.w, fmaf(h1, w1.w, fmaf(h0, w0.w, acc[ee][3]))));
                }
            }
        }
        __syncthreads();
#pragma unroll
        for (int ee = 0; ee < 3; ++ee) {
            int e = e0 + ee;
            if (e < EE) {
#pragma unroll
                for (int ccc = 0; ccc < 4; ++ccc)
                    s_af[e][c0+ccc] = acc[ee][ccc] + ab2[c0+ccc];
            }
        }
    }
    __syncthreads();
    ln_elu_f32<CO>(&s_af[0][0], EE, ag2, abt2);
    __syncthreads();
    // softmax over 21 neighbors + weighted aggregate
    if (t < CO) {
        int c = t;
        float af[EE]; float mx = -INFINITY;
#pragma unroll
        for (int e = 0; e < EE; ++e) { af[e] = s_af[e][c]; mx = fmaxf(mx, af[e]); }
        float ssum = 0.f;
#pragma unroll
        for (int e = 0; e < EE; ++e) { af[e] = expf(af[e] - mx); ssum += af[e]; }
        float accv = 0.f;
#pragma unroll
        for (int e = 0; e < EE; ++e) {
            int j = s_idx[e];
            float msg = v[j*CO + c] + b2f(delta[(size_t)(i*EE + e)*CO + c]);
            accv = fmaf(af[e], msg, accv);
        }
        out[i*CO + c] = accv / ssum;
    }
}

extern "C" void kernel_launch(void* const* d_in, const int* in_sizes, int n_in,
                              void* d_out, int out_size, void* d_ws, size_t ws_size,
                              hipStream_t stream)
{
    const float* x    = (const float*)d_in[0];
    const float* pos  = (const float*)d_in[1];
    const float* Wl   = (const float*)d_in[3];
    const float* Wsrc = (const float*)d_in[4];
    const float* Wdst = (const float*)d_in[5];
    const float* pw1  = (const float*)d_in[6];
    const float* pb1  = (const float*)d_in[7];
    const float* pg1  = (const float*)d_in[8];
    const float* pbt1 = (const float*)d_in[9];
    const float* pw2  = (const float*)d_in[10];
    const float* pb2  = (const float*)d_in[11];
    const float* pg2  = (const float*)d_in[12];
    const float* pbt2 = (const float*)d_in[13];
    const float* aw1  = (const float*)d_in[14];
    const float* ab1  = (const float*)d_in[15];
    const float* ag1  = (const float*)d_in[16];
    const float* abt1 = (const float*)d_in[17];
    const float* aw2  = (const float*)d_in[18];
    const float* ab2  = (const float*)d_in[19];
    const float* ag2  = (const float*)d_in[20];
    const float* abt2 = (const float*)d_in[21];
    float* out = (float*)d_out;

    char* ws = (char*)d_ws;
    int*   idxg  = (int*)ws;                               // 344064 B
    float* v     = (float*)(ws + 0x80000);                 // 2 MB
    float* asrc  = (float*)(ws + 0x80000 + 0x200000);      // 2 MB
    float* adst  = (float*)(ws + 0x80000 + 0x400000);      // 2 MB
    u16*   delta = (u16*)(ws + 0x80000 + 0x600000);        // 22 MB (bf16)

    k_knn  <<<NN,        64,  0, stream>>>(pos, idxg);
    k_lin3 <<<NN/8,      256, 0, stream>>>(x, Wl, Wsrc, Wdst, v, asrc, adst);
    k_posnn<<<EDGES/32,  256, 0, stream>>>(pos, idxg, pw1, pb1, pg1, pbt1,
                                           pw2, pb2, pg2, pbt2, delta);
    k_attn <<<NN,        256, 0, stream>>>(idxg, v, asrc, adst, delta,
                                           aw1, ab1, ag1, abt1,
                                           aw2, ab2, ag2, abt2, out);
}

// Round 2
// 1146.997 us; speedup vs baseline: 1.2092x; 1.2092x over previous
//
#include <hip/hip_runtime.h>
#include <math.h>

#define NN    4096
#define CIN   128
#define CO    128
#define HD    512
#define KK    20
#define EE    21
#define EDGES (NN * EE)   // 86016
#define LNEPS 1e-5f

typedef unsigned short u16;
typedef unsigned int   u32;
typedef unsigned long long u64;

__device__ __forceinline__ u16 f2b(float x) {
    u32 u = __float_as_uint(x);
    u32 r = u + 0x7fffu + ((u >> 16) & 1u);   // round-to-nearest-even
    return (u16)(r >> 16);
}
__device__ __forceinline__ float b2f(u16 h) {
    return __uint_as_float(((u32)h) << 16);
}

// ---------------- kNN: 1 wave per node ----------------
__global__ __launch_bounds__(64) void k_knn(const float* __restrict__ pos,
                                            int* __restrict__ idxg)
{
    int i = blockIdx.x;
    int lane = threadIdx.x;
    float px = pos[3*i], py = pos[3*i+1], pz = pos[3*i+2];
    float bd[KK]; int bi[KK];
#pragma unroll
    for (int s = 0; s < KK; ++s) { bd[s] = INFINITY; bi[s] = 0x7fffffff; }
    for (int j = lane; j < NN; j += 64) {
        float dx = px - pos[3*j], dy = py - pos[3*j+1], dz = pz - pos[3*j+2];
        float d2 = dx*dx + dy*dy + dz*dz;
        if (j != i && d2 < bd[KK-1]) {
            float cd = d2; int ci = j;
#pragma unroll
            for (int s = 0; s < KK; ++s) {   // static-index bubble insert
                bool sw = cd < bd[s];
                float td = sw ? bd[s] : cd;  int ti = sw ? bi[s] : ci;
                bd[s] = sw ? cd : bd[s];     bi[s] = sw ? ci : bi[s];
                cd = td; ci = ti;
            }
        }
    }
    for (int r = 0; r < KK; ++r) {
        u64 m = ~0ull;
#pragma unroll
        for (int s = 0; s < KK; ++s) {
            u64 k = ((u64)__float_as_uint(bd[s]) << 32) | (u32)bi[s];
            m = k < m ? k : m;
        }
#pragma unroll
        for (int off = 32; off > 0; off >>= 1) {
            u64 o = __shfl_xor(m, off, 64);
            m = o < m ? o : m;
        }
        if (lane == 0) idxg[i*EE + r] = (int)(u32)m;
#pragma unroll
        for (int s = 0; s < KK; ++s) {
            u64 k = ((u64)__float_as_uint(bd[s]) << 32) | (u32)bi[s];
            if (k == m) bd[s] = INFINITY;
        }
    }
    if (lane == 0) idxg[i*EE + KK] = i;   // self-loop appended
}

// ---------------- v / a_src / a_dst ----------------
__global__ __launch_bounds__(256) void k_lin3(const float* __restrict__ x,
        const float* __restrict__ Wl, const float* __restrict__ Ws, const float* __restrict__ Wd,
        float* __restrict__ v, float* __restrict__ as_, float* __restrict__ ad)
{
    __shared__ float sx[8][CIN];
    int b = blockIdx.x, t = threadIdx.x;
    int n0 = b * 8;
    for (int q = t; q < 8*CIN; q += 256) sx[q >> 7][q & 127] = x[n0*CIN + q];
    __syncthreads();
    int c = t & 127, g = t >> 7;
    float al[4] = {0,0,0,0}, asr[4] = {0,0,0,0}, adr[4] = {0,0,0,0};
    for (int k = 0; k < CIN; ++k) {
        float wl = Wl[k*CO + c], ws = Ws[k*CO + c], wd = Wd[k*CO + c];
#pragma unroll
        for (int nn2 = 0; nn2 < 4; ++nn2) {
            float xv = sx[g*4 + nn2][k];
            al[nn2]  = fmaf(xv, wl, al[nn2]);
            asr[nn2] = fmaf(xv, ws, asr[nn2]);
            adr[nn2] = fmaf(xv, wd, adr[nn2]);
        }
    }
#pragma unroll
    for (int nn2 = 0; nn2 < 4; ++nn2) {
        int n = n0 + g*4 + nn2;
        v[n*CO + c]   = al[nn2];
        as_[n*CO + c] = asr[nn2];
        ad[n*CO + c]  = adr[nn2];
    }
}

// ---------------- LayerNorm + ELU helpers (rows in LDS) ----------------
template<int L>
__device__ __forceinline__ void ln_elu_b16(u16* base, int rows,
        const float* __restrict__ gam, const float* __restrict__ bet)
{
    int t = threadIdx.x, lane = t & 63, w = t >> 6;
    constexpr int P = L / 64;
    for (int e = w; e < rows; e += 4) {
        u16* row = base + e * L;
        float vals[P]; float s = 0.f, sq = 0.f;
#pragma unroll
        for (int q = 0; q < P; ++q) {
            float xx = b2f(row[lane + q*64]);
            vals[q] = xx; s += xx; sq += xx*xx;
        }
#pragma unroll
        for (int off = 32; off > 0; off >>= 1) {
            s  += __shfl_xor(s,  off, 64);
            sq += __shfl_xor(sq, off, 64);
        }
        float mn = s * (1.0f / L);
        float var = sq * (1.0f / L) - mn*mn;
        float rstd = rsqrtf(var + LNEPS);
#pragma unroll
        for (int q = 0; q < P; ++q) {
            int cc = lane + q*64;
            float y = (vals[q] - mn) * rstd * gam[cc] + bet[cc];
            y = y > 0.f ? y : expm1f(y);
            row[cc] = f2b(y);
        }
    }
}

template<int L>
__device__ __forceinline__ void ln_elu_f32(float* base, int rows,
        const float* __restrict__ gam, const float* __restrict__ bet)
{
    int t = threadIdx.x, lane = t & 63, w = t >> 6;
    constexpr int P = L / 64;
    for (int e = w; e < rows; e += 4) {
        float* row = base + e * L;
        float vals[P]; float s = 0.f, sq = 0.f;
#pragma unroll
        for (int q = 0; q < P; ++q) {
            float xx = row[lane + q*64];
            vals[q] = xx; s += xx; sq += xx*xx;
        }
#pragma unroll
        for (int off = 32; off > 0; off >>= 1) {
            s  += __shfl_xor(s,  off, 64);
            sq += __shfl_xor(sq, off, 64);
        }
        float mn = s * (1.0f / L);
        float var = sq * (1.0f / L) - mn*mn;
        float rstd = rsqrtf(var + LNEPS);
#pragma unroll
        for (int q = 0; q < P; ++q) {
            int cc = lane + q*64;
            float y = (vals[q] - mn) * rstd * gam[cc] + bet[cc];
            y = y > 0.f ? y : expm1f(y);
            row[cc] = y;
        }
    }
}

// ---------------- pos_nn: rel -> h(512) -> LN/ELU -> delta(128) -> LN/ELU ----------------
__global__ __launch_bounds__(256) void k_posnn(
        const float* __restrict__ pos, const int* __restrict__ idxg,
        const float* __restrict__ pw1, const float* __restrict__ pb1,
        const float* __restrict__ pg1, const float* __restrict__ pbt1,
        const float* __restrict__ pw2, const float* __restrict__ pb2,
        const float* __restrict__ pg2, const float* __restrict__ pbt2,
        u16* __restrict__ delta)
{
    __shared__ u16   s_h[32][HD];     // 32 KB, bf16 hidden
    __shared__ float s_d[32][CO];     // 16 KB
    __shared__ __align__(16) float s_w[32*CO];      // 16 KB weight stage
    __shared__ float s_rel[32][3];
    int t = threadIdx.x;
    int e0g = blockIdx.x * 32;        // 86016 / 32 = 2688 exact
    if (t < 32) {
        int e = e0g + t;
        u32 ii = (u32)e / 21u;
        int j = idxg[e];
        s_rel[t][0] = pos[3*ii]   - pos[3*j];
        s_rel[t][1] = pos[3*ii+1] - pos[3*j+1];
        s_rel[t][2] = pos[3*ii+2] - pos[3*j+2];
    }
    __syncthreads();
    {   // layer P1
        int c1 = t, c2 = t + 256;
        float wa0 = pw1[c1], wa1 = pw1[HD + c1], wa2 = pw1[2*HD + c1], ba = pb1[c1];
        float wb0 = pw1[c2], wb1 = pw1[HD + c2], wb2 = pw1[2*HD + c2], bb = pb1[c2];
        for (int r = 0; r < 32; ++r) {
            float r0 = s_rel[r][0], r1 = s_rel[r][1], r2 = s_rel[r][2];
            s_h[r][c1] = f2b(ba + r0*wa0 + r1*wa1 + r2*wa2);
            s_h[r][c2] = f2b(bb + r0*wb0 + r1*wb1 + r2*wb2);
        }
    }
    __syncthreads();
    ln_elu_b16<HD>(&s_h[0][0], 32, pg1, pbt1);
    __syncthreads();
    // layer P2: delta = h @ pw2 + pb2 ; thread tile: 4 edges x 4 cols
    int cq = t & 31, c0 = 4*cq, eg = t >> 5, e0 = eg*4;
    float acc[4][4];
#pragma unroll
    for (int a = 0; a < 4; ++a)
#pragma unroll
        for (int b = 0; b < 4; ++b) acc[a][b] = 0.f;
    for (int kc = 0; kc < HD; kc += 32) {
        __syncthreads();
        for (int q = t*4; q < 32*CO; q += 1024)
            *(float4*)&s_w[q] = *(const float4*)&pw2[kc*CO + q];
        __syncthreads();
        for (int k0 = 0; k0 < 32; k0 += 4) {
            float4 w0 = *(const float4*)&s_w[(k0+0)*CO + c0];
            float4 w1 = *(const float4*)&s_w[(k0+1)*CO + c0];
            float4 w2 = *(const float4*)&s_w[(k0+2)*CO + c0];
            float4 w3 = *(const float4*)&s_w[(k0+3)*CO + c0];
#pragma unroll
            for (int ee = 0; ee < 4; ++ee) {
                ushort4 hu = *(const ushort4*)&s_h[e0+ee][kc + k0];
                float h0 = b2f(hu.x), h1 = b2f(hu.y), h2 = b2f(hu.z), h3 = b2f(hu.w);
                acc[ee][0] = fmaf(h3, w3.x, fmaf(h2, w2.x, fmaf(h1, w1.x, fmaf(h0, w0.x, acc[ee][0]))));
                acc[ee][1] = fmaf(h3, w3.y, fmaf(h2, w2.y, fmaf(h1, w1.y, fmaf(h0, w0.y, acc[ee][1]))));
                acc[ee][2] = fmaf(h3, w3.z, fmaf(h2, w2.z, fmaf(h1, w1.z, fmaf(h0, w0.z, acc[ee][2]))));
                acc[ee][3] = fmaf(h3, w3.w, fmaf(h2, w2.w, fmaf(h1, w1.w, fmaf(h0, w0.w, acc[ee][3]))));
            }
        }
    }
    __syncthreads();
#pragma unroll
    for (int ee = 0; ee < 4; ++ee)
#pragma unroll
        for (int ccc = 0; ccc < 4; ++ccc)
            s_d[e0+ee][c0+ccc] = acc[ee][ccc] + pb2[c0+ccc];
    __syncthreads();
    ln_elu_f32<CO>(&s_d[0][0], 32, pg2, pbt2);
    __syncthreads();
    for (int q = t; q < 32*CO; q += 256)
        delta[(size_t)e0g*CO + q] = f2b(s_d[q >> 7][q & 127]);
}

// ---------------- attn MLP (edge-tiled): alpha0 -> LN/ELU MLP -> alphaF ----------------
__global__ __launch_bounds__(256) void k_amlp(
        const int* __restrict__ idxg,
        const float* __restrict__ as_, const float* __restrict__ ad,
        const u16* __restrict__ delta,
        const float* __restrict__ aw1, const float* __restrict__ ab1,
        const float* __restrict__ ag1, const float* __restrict__ abt1,
        const float* __restrict__ aw2, const float* __restrict__ ab2,
        const float* __restrict__ ag2, const float* __restrict__ abt2,
        u16* __restrict__ alphaF)
{
    __shared__ u16   s_a[32][CIN];               // 8 KB alpha0 bf16
    __shared__ u16   s_h[32][HD];                // 32 KB hidden bf16
    __shared__ float s_af[32][CO];               // 16 KB
    __shared__ __align__(16) u16 s_w16[16*HD];   // 16 KB (A1 bf16 chunk / A2 f32 chunk alias)
    float* s_wf = (float*)s_w16;
    int t = threadIdx.x;
    int e0g = blockIdx.x * 32;
    // alpha0 = a_dst[i] - a_src[j] + delta
    for (int q = t; q < 32*CIN; q += 256) {
        int el = q >> 7, c = q & 127;
        int e = e0g + el;
        int i = (int)((u32)e / 21u);
        int j = idxg[e];
        float val = ad[i*CIN + c] - as_[j*CIN + c] + b2f(delta[(size_t)e*CO + c]);
        s_a[el][c] = f2b(val);
    }
    __syncthreads();
    {   // A1: h = alpha0 @ aw1 ; [32,128]@[128,512]; thread: 16 edges x 4 cols
        int cq = t & 127, c0 = 4*cq, eg = t >> 7, e0 = eg*16;
        float acc[16][4];
#pragma unroll
        for (int a = 0; a < 16; ++a)
#pragma unroll
            for (int b = 0; b < 4; ++b) acc[a][b] = 0.f;
        for (int kc = 0; kc < CIN; kc += 16) {
            __syncthreads();
            for (int q = t; q < 16*HD; q += 256)
                s_w16[q] = f2b(aw1[(size_t)(kc + (q >> 9))*HD + (q & 511)]);
            __syncthreads();
#pragma unroll
            for (int k0 = 0; k0 < 16; k0 += 4) {
                ushort4 u0 = *(const ushort4*)&s_w16[(k0+0)*HD + c0];
                ushort4 u1 = *(const ushort4*)&s_w16[(k0+1)*HD + c0];
                ushort4 u2 = *(const ushort4*)&s_w16[(k0+2)*HD + c0];
                ushort4 u3 = *(const ushort4*)&s_w16[(k0+3)*HD + c0];
                float w00=b2f(u0.x),w01=b2f(u0.y),w02=b2f(u0.z),w03=b2f(u0.w);
                float w10=b2f(u1.x),w11=b2f(u1.y),w12=b2f(u1.z),w13=b2f(u1.w);
                float w20=b2f(u2.x),w21=b2f(u2.y),w22=b2f(u2.z),w23=b2f(u2.w);
                float w30=b2f(u3.x),w31=b2f(u3.y),w32=b2f(u3.z),w33=b2f(u3.w);
#pragma unroll
                for (int ee = 0; ee < 16; ++ee) {
                    ushort4 au = *(const ushort4*)&s_a[e0+ee][kc + k0];
                    float a0 = b2f(au.x), a1 = b2f(au.y), a2 = b2f(au.z), a3 = b2f(au.w);
                    acc[ee][0] = fmaf(a3, w30, fmaf(a2, w20, fmaf(a1, w10, fmaf(a0, w00, acc[ee][0]))));
                    acc[ee][1] = fmaf(a3, w31, fmaf(a2, w21, fmaf(a1, w11, fmaf(a0, w01, acc[ee][1]))));
                    acc[ee][2] = fmaf(a3, w32, fmaf(a2, w22, fmaf(a1, w12, fmaf(a0, w02, acc[ee][2]))));
                    acc[ee][3] = fmaf(a3, w33, fmaf(a2, w23, fmaf(a1, w13, fmaf(a0, w03, acc[ee][3]))));
                }
            }
        }
        float4 bb = *(const float4*)&ab1[c0];
        __syncthreads();
#pragma unroll
        for (int ee = 0; ee < 16; ++ee) {
            ushort4 hv;
            hv.x = f2b(acc[ee][0] + bb.x);
            hv.y = f2b(acc[ee][1] + bb.y);
            hv.z = f2b(acc[ee][2] + bb.z);
            hv.w = f2b(acc[ee][3] + bb.w);
            *(ushort4*)&s_h[e0+ee][c0] = hv;
        }
    }
    __syncthreads();
    ln_elu_b16<HD>(&s_h[0][0], 32, ag1, abt1);
    __syncthreads();
    {   // A2: alphaF = h @ aw2 ; [32,512]@[512,128]; thread: 4 edges x 4 cols
        int cq = t & 31, c0 = 4*cq, eg = t >> 5, e0 = eg*4;
        float acc[4][4];
#pragma unroll
        for (int a = 0; a < 4; ++a)
#pragma unroll
            for (int b = 0; b < 4; ++b) acc[a][b] = 0.f;
        for (int kc = 0; kc < HD; kc += 32) {
            __syncthreads();
            for (int q = t*4; q < 32*CO; q += 1024)
                *(float4*)&s_wf[q] = *(const float4*)&aw2[kc*CO + q];
            __syncthreads();
            for (int k0 = 0; k0 < 32; k0 += 4) {
                float4 w0 = *(const float4*)&s_wf[(k0+0)*CO + c0];
                float4 w1 = *(const float4*)&s_wf[(k0+1)*CO + c0];
                float4 w2 = *(const float4*)&s_wf[(k0+2)*CO + c0];
                float4 w3 = *(const float4*)&s_wf[(k0+3)*CO + c0];
#pragma unroll
                for (int ee = 0; ee < 4; ++ee) {
                    ushort4 hu = *(const ushort4*)&s_h[e0+ee][kc + k0];
                    float h0 = b2f(hu.x), h1 = b2f(hu.y), h2 = b2f(hu.z), h3 = b2f(hu.w);
                    acc[ee][0] = fmaf(h3, w3.x, fmaf(h2, w2.x, fmaf(h1, w1.x, fmaf(h0, w0.x, acc[ee][0]))));
                    acc[ee][1] = fmaf(h3, w3.y, fmaf(h2, w2.y, fmaf(h1, w1.y, fmaf(h0, w0.y, acc[ee][1]))));
                    acc[ee][2] = fmaf(h3, w3.z, fmaf(h2, w2.z, fmaf(h1, w1.z, fmaf(h0, w0.z, acc[ee][2]))));
                    acc[ee][3] = fmaf(h3, w3.w, fmaf(h2, w2.w, fmaf(h1, w1.w, fmaf(h0, w0.w, acc[ee][3]))));
                }
            }
        }
        __syncthreads();
#pragma unroll
        for (int ee = 0; ee < 4; ++ee)
#pragma unroll
            for (int ccc = 0; ccc < 4; ++ccc)
                s_af[e0+ee][c0+ccc] = acc[ee][ccc] + ab2[c0+ccc];
    }
    __syncthreads();
    ln_elu_f32<CO>(&s_af[0][0], 32, ag2, abt2);
    __syncthreads();
    for (int q = t; q < 32*CO; q += 256)
        alphaF[(size_t)e0g*CO + q] = f2b(s_af[q >> 7][q & 127]);
}

// ---------------- softmax over neighbors + weighted aggregate ----------------
__global__ __launch_bounds__(256) void k_agg(
        const int* __restrict__ idxg,
        const float* __restrict__ v, const u16* __restrict__ delta,
        const u16* __restrict__ alphaF, float* __restrict__ out)
{
    __shared__ int s_idx[8][EE];
    int b = blockIdx.x, t = threadIdx.x;
    int n0 = b * 8;
    for (int q = t; q < 8*EE; q += 256) s_idx[q/EE][q%EE] = idxg[n0*EE + q];
    __syncthreads();
    int c = t & 127, g = t >> 7;
    for (int ng = g; ng < 8; ng += 2) {
        int i = n0 + ng;
        size_t base = (size_t)i*EE*CO + c;
        float af[EE]; float mx = -INFINITY;
#pragma unroll
        for (int e = 0; e < EE; ++e) { af[e] = b2f(alphaF[base + e*CO]); mx = fmaxf(mx, af[e]); }
        float ssum = 0.f;
#pragma unroll
        for (int e = 0; e < EE; ++e) { af[e] = expf(af[e] - mx); ssum += af[e]; }
        float accv = 0.f;
#pragma unroll
        for (int e = 0; e < EE; ++e) {
            int j = s_idx[ng][e];
            float msg = v[j*CO + c] + b2f(delta[base + e*CO]);
            accv = fmaf(af[e], msg, accv);
        }
        out[i*CO + c] = accv / ssum;
    }
}

extern "C" void kernel_launch(void* const* d_in, const int* in_sizes, int n_in,
                              void* d_out, int out_size, void* d_ws, size_t ws_size,
                              hipStream_t stream)
{
    const float* x    = (const float*)d_in[0];
    const float* pos  = (const float*)d_in[1];
    const float* Wl   = (const float*)d_in[3];
    const float* Wsrc = (const float*)d_in[4];
    const float* Wdst = (const float*)d_in[5];
    const float* pw1  = (const float*)d_in[6];
    const float* pb1  = (const float*)d_in[7];
    const float* pg1  = (const float*)d_in[8];
    const float* pbt1 = (const float*)d_in[9];
    const float* pw2  = (const float*)d_in[10];
    const float* pb2  = (const float*)d_in[11];
    const float* pg2  = (const float*)d_in[12];
    const float* pbt2 = (const float*)d_in[13];
    const float* aw1  = (const float*)d_in[14];
    const float* ab1  = (const float*)d_in[15];
    const float* ag1  = (const float*)d_in[16];
    const float* abt1 = (const float*)d_in[17];
    const float* aw2  = (const float*)d_in[18];
    const float* ab2  = (const float*)d_in[19];
    const float* ag2  = (const float*)d_in[20];
    const float* abt2 = (const float*)d_in[21];
    float* out = (float*)d_out;

    char* ws = (char*)d_ws;
    int*   idxg   = (int*)ws;                                // 344064 B
    float* v      = (float*)(ws + 0x80000);                  // 2 MB
    float* asrc   = (float*)(ws + 0x280000);                 // 2 MB
    float* adst   = (float*)(ws + 0x480000);                 // 2 MB
    u16*   delta  = (u16*)(ws + 0x680000);                   // 22020096 B (bf16)
    u16*   alphaF = (u16*)(ws + 0x680000 + 0x1500000);       // 22020096 B (bf16)

    k_knn  <<<NN,        64,  0, stream>>>(pos, idxg);
    k_lin3 <<<NN/8,      256, 0, stream>>>(x, Wl, Wsrc, Wdst, v, asrc, adst);
    k_posnn<<<EDGES/32,  256, 0, stream>>>(pos, idxg, pw1, pb1, pg1, pbt1,
                                           pw2, pb2, pg2, pbt2, delta);
    k_amlp <<<EDGES/32,  256, 0, stream>>>(idxg, asrc, adst, delta,
                                           aw1, ab1, ag1, abt1,
                                           aw2, ab2, ag2, abt2, alphaF);
    k_agg  <<<NN/8,      256, 0, stream>>>(idxg, v, delta, alphaF, out);
}

// Round 3
// 356.231 us; speedup vs baseline: 3.8933x; 3.2198x over previous
//
#include <hip/hip_runtime.h>
#include <math.h>

#define NN    4096
#define CIN   128
#define CO    128
#define HD    512
#define KK    20
#define EE    21
#define EDGES (NN * EE)   // 86016
#define LNEPS 1e-5f

typedef unsigned short u16;
typedef unsigned int   u32;
typedef unsigned long long u64;
typedef __attribute__((ext_vector_type(8))) short bf16x8;
typedef __attribute__((ext_vector_type(4))) float f32x4;

#define MFMA16(a,b,c) __builtin_amdgcn_mfma_f32_16x16x32_bf16(a,b,c,0,0,0)

__device__ __forceinline__ u16 f2b(float x) {
    u32 u = __float_as_uint(x);
    u32 r = u + 0x7fffu + ((u >> 16) & 1u);   // round-to-nearest-even
    return (u16)(r >> 16);
}
__device__ __forceinline__ float b2f(u16 h) {
    return __uint_as_float(((u32)h) << 16);
}

// ---------------- kNN: 1 wave per node ----------------
__global__ __launch_bounds__(64) void k_knn(const float* __restrict__ pos,
                                            int* __restrict__ idxg)
{
    int i = blockIdx.x;
    int lane = threadIdx.x;
    float px = pos[3*i], py = pos[3*i+1], pz = pos[3*i+2];
    float bd[KK]; int bi[KK];
#pragma unroll
    for (int s = 0; s < KK; ++s) { bd[s] = INFINITY; bi[s] = 0x7fffffff; }
    for (int j = lane; j < NN; j += 64) {
        float dx = px - pos[3*j], dy = py - pos[3*j+1], dz = pz - pos[3*j+2];
        float d2 = dx*dx + dy*dy + dz*dz;
        if (j != i && d2 < bd[KK-1]) {
            float cd = d2; int ci = j;
#pragma unroll
            for (int s = 0; s < KK; ++s) {   // static-index bubble insert
                bool sw = cd < bd[s];
                float td = sw ? bd[s] : cd;  int ti = sw ? bi[s] : ci;
                bd[s] = sw ? cd : bd[s];     bi[s] = sw ? ci : bi[s];
                cd = td; ci = ti;
            }
        }
    }
    for (int r = 0; r < KK; ++r) {
        u64 m = ~0ull;
#pragma unroll
        for (int s = 0; s < KK; ++s) {
            u64 k = ((u64)__float_as_uint(bd[s]) << 32) | (u32)bi[s];
            m = k < m ? k : m;
        }
#pragma unroll
        for (int off = 32; off > 0; off >>= 1) {
            u64 o = __shfl_xor(m, off, 64);
            m = o < m ? o : m;
        }
        if (lane == 0) idxg[i*EE + r] = (int)(u32)m;
#pragma unroll
        for (int s = 0; s < KK; ++s) {
            u64 k = ((u64)__float_as_uint(bd[s]) << 32) | (u32)bi[s];
            if (k == m) bd[s] = INFINITY;
        }
    }
    if (lane == 0) idxg[i*EE + KK] = i;   // self-loop appended
}

// ---------------- v / a_src / a_dst ----------------
__global__ __launch_bounds__(256) void k_lin3(const float* __restrict__ x,
        const float* __restrict__ Wl, const float* __restrict__ Ws, const float* __restrict__ Wd,
        float* __restrict__ v, float* __restrict__ as_, float* __restrict__ ad)
{
    __shared__ float sx[8][CIN];
    int b = blockIdx.x, t = threadIdx.x;
    int n0 = b * 8;
    for (int q = t; q < 8*CIN; q += 256) sx[q >> 7][q & 127] = x[n0*CIN + q];
    __syncthreads();
    int c = t & 127, g = t >> 7;
    float al[4] = {0,0,0,0}, asr[4] = {0,0,0,0}, adr[4] = {0,0,0,0};
    for (int k = 0; k < CIN; ++k) {
        float wl = Wl[k*CO + c], ws = Ws[k*CO + c], wd = Wd[k*CO + c];
#pragma unroll
        for (int nn2 = 0; nn2 < 4; ++nn2) {
            float xv = sx[g*4 + nn2][k];
            al[nn2]  = fmaf(xv, wl, al[nn2]);
            asr[nn2] = fmaf(xv, ws, asr[nn2]);
            adr[nn2] = fmaf(xv, wd, adr[nn2]);
        }
    }
#pragma unroll
    for (int nn2 = 0; nn2 < 4; ++nn2) {
        int n = n0 + g*4 + nn2;
        v[n*CO + c]   = al[nn2];
        as_[n*CO + c] = asr[nn2];
        ad[n*CO + c]  = adr[nn2];
    }
}

// ---------------- weight prepack: f32 [K][N] -> bf16 frag-major [N/16][K/32][64][8] ----------------
__global__ __launch_bounds__(256) void k_wconv(const float* __restrict__ src,
        u16* __restrict__ dst, int N, int kplog)
{
    int idx = blockIdx.x * 256 + threadIdx.x;
    int j  = idx & 7;
    int l  = (idx >> 3) & 63;
    int ks = (idx >> 9) & ((1 << kplog) - 1);
    int nt = idx >> (9 + kplog);
    int k = ks*32 + (l >> 4)*8 + j;
    int c = nt*16 + (l & 15);
    dst[idx] = f2b(src[(size_t)k*N + c]);
}

// ---------------- LayerNorm + ELU helpers (rows in LDS, padded stride) ----------------
template<int L>
__device__ __forceinline__ void ln_elu_b16(u16* base, int rows, int stride,
        const float* __restrict__ gam, const float* __restrict__ bet)
{
    int t = threadIdx.x, lane = t & 63, w = t >> 6;
    constexpr int P = L / 64;
    for (int e = w; e < rows; e += 4) {
        u16* row = base + e * stride;
        float vals[P]; float s = 0.f, sq = 0.f;
#pragma unroll
        for (int q = 0; q < P; ++q) {
            float xx = b2f(row[lane + q*64]);
            vals[q] = xx; s += xx; sq += xx*xx;
        }
#pragma unroll
        for (int off = 32; off > 0; off >>= 1) {
            s  += __shfl_xor(s,  off, 64);
            sq += __shfl_xor(sq, off, 64);
        }
        float mn = s * (1.0f / L);
        float var = sq * (1.0f / L) - mn*mn;
        float rstd = rsqrtf(var + LNEPS);
#pragma unroll
        for (int q = 0; q < P; ++q) {
            int cc = lane + q*64;
            float y = (vals[q] - mn) * rstd * gam[cc] + bet[cc];
            y = y > 0.f ? y : expm1f(y);
            row[cc] = f2b(y);
        }
    }
}

template<int L>
__device__ __forceinline__ void ln_elu_f32(float* base, int rows, int stride,
        const float* __restrict__ gam, const float* __restrict__ bet)
{
    int t = threadIdx.x, lane = t & 63, w = t >> 6;
    constexpr int P = L / 64;
    for (int e = w; e < rows; e += 4) {
        float* row = base + e * stride;
        float vals[P]; float s = 0.f, sq = 0.f;
#pragma unroll
        for (int q = 0; q < P; ++q) {
            float xx = row[lane + q*64];
            vals[q] = xx; s += xx; sq += xx*xx;
        }
#pragma unroll
        for (int off = 32; off > 0; off >>= 1) {
            s  += __shfl_xor(s,  off, 64);
            sq += __shfl_xor(sq, off, 64);
        }
        float mn = s * (1.0f / L);
        float var = sq * (1.0f / L) - mn*mn;
        float rstd = rsqrtf(var + LNEPS);
#pragma unroll
        for (int q = 0; q < P; ++q) {
            int cc = lane + q*64;
            float y = (vals[q] - mn) * rstd * gam[cc] + bet[cc];
            y = y > 0.f ? y : expm1f(y);
            row[cc] = y;
        }
    }
}

// strides (padded: +8 bf16 / +4 f32 keeps ds_read_b128 bank-uniform)
#define SA_S 136
#define SH_S 520
#define SF_S 132

// ---------------- pos_nn: rel -> h(512) -> LN/ELU -> delta(128) -> LN/ELU ----------------
__global__ __launch_bounds__(256) void k_posnn(
        const float* __restrict__ pos, const int* __restrict__ idxg,
        const float* __restrict__ pw1, const float* __restrict__ pb1,
        const float* __restrict__ pg1, const float* __restrict__ pbt1,
        const u16* __restrict__ pwp2, const float* __restrict__ pb2,
        const float* __restrict__ pg2, const float* __restrict__ pbt2,
        u16* __restrict__ delta)
{
    __shared__ __align__(16) u16   s_h[32*SH_S];
    __shared__ __align__(16) float s_d[32*SF_S];
    __shared__ float s_rel[32][3];
    int t = threadIdx.x;
    int e0g = blockIdx.x * 32;        // 86016 / 32 = 2688 exact
    if (t < 32) {
        int e = e0g + t;
        u32 ii = (u32)e / 21u;
        int j = idxg[e];
        s_rel[t][0] = pos[3*ii]   - pos[3*j];
        s_rel[t][1] = pos[3*ii+1] - pos[3*j+1];
        s_rel[t][2] = pos[3*ii+2] - pos[3*j+2];
    }
    __syncthreads();
    {   // P1: h = rel @ pw1 + pb1 (each thread: 2 channels, all 32 rows)
        int c1 = t, c2 = t + 256;
        float wa0 = pw1[c1], wa1 = pw1[HD + c1], wa2 = pw1[2*HD + c1], ba = pb1[c1];
        float wb0 = pw1[c2], wb1 = pw1[HD + c2], wb2 = pw1[2*HD + c2], bb = pb1[c2];
        for (int r = 0; r < 32; ++r) {
            float r0 = s_rel[r][0], r1 = s_rel[r][1], r2 = s_rel[r][2];
            s_h[r*SH_S + c1] = f2b(ba + r0*wa0 + r1*wa1 + r2*wa2);
            s_h[r*SH_S + c2] = f2b(bb + r0*wb0 + r1*wb1 + r2*wb2);
        }
    }
    __syncthreads();
    ln_elu_b16<HD>(s_h, 32, SH_S, pg1, pbt1);
    __syncthreads();
    {   // P2 (MFMA): delta = h @ pw2 ; [32,512]@[512,128]
        int w = t >> 6, l = t & 63, lr = l & 15, lk = l >> 4;
        int m = w & 1, nt0 = (w >> 1) * 4;
        bf16x8 afr[16];
#pragma unroll
        for (int ks = 0; ks < 16; ++ks)
            afr[ks] = *(const bf16x8*)&s_h[(m*16 + lr)*SH_S + ks*32 + lk*8];
#pragma unroll
        for (int n2 = 0; n2 < 4; ++n2) {
            int nt = nt0 + n2;
            const u16* bp = pwp2 + ((size_t)nt*16*64 + l)*8;
            f32x4 acc = {0.f, 0.f, 0.f, 0.f};
#pragma unroll
            for (int ks = 0; ks < 16; ++ks) {
                bf16x8 bfr = *(const bf16x8*)(bp + ks*512);
                acc = MFMA16(afr[ks], bfr, acc);
            }
            float bias = pb2[nt*16 + lr];
#pragma unroll
            for (int r = 0; r < 4; ++r)
                s_d[(m*16 + lk*4 + r)*SF_S + nt*16 + lr] = acc[r] + bias;
        }
    }
    __syncthreads();
    ln_elu_f32<CO>(s_d, 32, SF_S, pg2, pbt2);
    __syncthreads();
    for (int q = t; q < 32*CO; q += 256)
        delta[(size_t)e0g*CO + q] = f2b(s_d[(q >> 7)*SF_S + (q & 127)]);
}

// ---------------- attn MLP (edge-tiled, MFMA) ----------------
__global__ __launch_bounds__(256) void k_amlp(
        const int* __restrict__ idxg,
        const float* __restrict__ as_, const float* __restrict__ ad,
        const u16* __restrict__ delta,
        const u16* __restrict__ awp1, const float* __restrict__ ab1,
        const float* __restrict__ ag1, const float* __restrict__ abt1,
        const u16* __restrict__ awp2, const float* __restrict__ ab2,
        const float* __restrict__ ag2, const float* __restrict__ abt2,
        u16* __restrict__ alphaF)
{
    __shared__ __align__(16) u16   s_a[32*SA_S];
    __shared__ __align__(16) u16   s_h[32*SH_S];
    __shared__ __align__(16) float s_af[32*SF_S];
    int t = threadIdx.x;
    int e0g = blockIdx.x * 32;
    // alpha0 = a_dst[i] - a_src[j] + delta
    for (int q = t; q < 32*CIN; q += 256) {
        int el = q >> 7, c = q & 127;
        int e = e0g + el;
        int i = (int)((u32)e / 21u);
        int j = idxg[e];
        float val = ad[i*CIN + c] - as_[j*CIN + c] + b2f(delta[(size_t)e*CO + c]);
        s_a[el*SA_S + c] = f2b(val);
    }
    __syncthreads();
    int w = t >> 6, l = t & 63, lr = l & 15, lk = l >> 4;
    {   // A1 (MFMA): h = alpha0 @ aw1 ; [32,128]@[128,512]
        int m = w & 1, nt0 = (w >> 1) * 16;
        bf16x8 afr[4];
#pragma unroll
        for (int ks = 0; ks < 4; ++ks)
            afr[ks] = *(const bf16x8*)&s_a[(m*16 + lr)*SA_S + ks*32 + lk*8];
#pragma unroll
        for (int n2 = 0; n2 < 16; ++n2) {
            int nt = nt0 + n2;
            const u16* bp = awp1 + ((size_t)nt*4*64 + l)*8;
            f32x4 acc = {0.f, 0.f, 0.f, 0.f};
#pragma unroll
            for (int ks = 0; ks < 4; ++ks) {
                bf16x8 bfr = *(const bf16x8*)(bp + ks*512);
                acc = MFMA16(afr[ks], bfr, acc);
            }
            float bias = ab1[nt*16 + lr];
#pragma unroll
            for (int r = 0; r < 4; ++r)
                s_h[(m*16 + lk*4 + r)*SH_S + nt*16 + lr] = f2b(acc[r] + bias);
        }
    }
    __syncthreads();
    ln_elu_b16<HD>(s_h, 32, SH_S, ag1, abt1);
    __syncthreads();
    {   // A2 (MFMA): alphaF = h @ aw2 ; [32,512]@[512,128]
        int m = w & 1, nt0 = (w >> 1) * 4;
        bf16x8 afr[16];
#pragma unroll
        for (int ks = 0; ks < 16; ++ks)
            afr[ks] = *(const bf16x8*)&s_h[(m*16 + lr)*SH_S + ks*32 + lk*8];
#pragma unroll
        for (int n2 = 0; n2 < 4; ++n2) {
            int nt = nt0 + n2;
            const u16* bp = awp2 + ((size_t)nt*16*64 + l)*8;
            f32x4 acc = {0.f, 0.f, 0.f, 0.f};
#pragma unroll
            for (int ks = 0; ks < 16; ++ks) {
                bf16x8 bfr = *(const bf16x8*)(bp + ks*512);
                acc = MFMA16(afr[ks], bfr, acc);
            }
            float bias = ab2[nt*16 + lr];
#pragma unroll
            for (int r = 0; r < 4; ++r)
                s_af[(m*16 + lk*4 + r)*SF_S + nt*16 + lr] = acc[r] + bias;
        }
    }
    __syncthreads();
    ln_elu_f32<CO>(s_af, 32, SF_S, ag2, abt2);
    __syncthreads();
    for (int q = t; q < 32*CO; q += 256)
        alphaF[(size_t)e0g*CO + q] = f2b(s_af[(q >> 7)*SF_S + (q & 127)]);
}

// ---------------- softmax over neighbors + weighted aggregate ----------------
__global__ __launch_bounds__(256) void k_agg(
        const int* __restrict__ idxg,
        const float* __restrict__ v, const u16* __restrict__ delta,
        const u16* __restrict__ alphaF, float* __restrict__ out)
{
    __shared__ int s_idx[8][EE];
    int b = blockIdx.x, t = threadIdx.x;
    int n0 = b * 8;
    for (int q = t; q < 8*EE; q += 256) s_idx[q/EE][q%EE] = idxg[n0*EE + q];
    __syncthreads();
    int c = t & 127, g = t >> 7;
    for (int ng = g; ng < 8; ng += 2) {
        int i = n0 + ng;
        size_t base = (size_t)i*EE*CO + c;
        float af[EE]; float mx = -INFINITY;
#pragma unroll
        for (int e = 0; e < EE; ++e) { af[e] = b2f(alphaF[base + e*CO]); mx = fmaxf(mx, af[e]); }
        float ssum = 0.f;
#pragma unroll
        for (int e = 0; e < EE; ++e) { af[e] = expf(af[e] - mx); ssum += af[e]; }
        float accv = 0.f;
#pragma unroll
        for (int e = 0; e < EE; ++e) {
            int j = s_idx[ng][e];
            float msg = v[j*CO + c] + b2f(delta[base + e*CO]);
            accv = fmaf(af[e], msg, accv);
        }
        out[i*CO + c] = accv / ssum;
    }
}

extern "C" void kernel_launch(void* const* d_in, const int* in_sizes, int n_in,
                              void* d_out, int out_size, void* d_ws, size_t ws_size,
                              hipStream_t stream)
{
    const float* x    = (const float*)d_in[0];
    const float* pos  = (const float*)d_in[1];
    const float* Wl   = (const float*)d_in[3];
    const float* Wsrc = (const float*)d_in[4];
    const float* Wdst = (const float*)d_in[5];
    const float* pw1  = (const float*)d_in[6];
    const float* pb1  = (const float*)d_in[7];
    const float* pg1  = (const float*)d_in[8];
    const float* pbt1 = (const float*)d_in[9];
    const float* pw2  = (const float*)d_in[10];
    const float* pb2  = (const float*)d_in[11];
    const float* pg2  = (const float*)d_in[12];
    const float* pbt2 = (const float*)d_in[13];
    const float* aw1  = (const float*)d_in[14];
    const float* ab1  = (const float*)d_in[15];
    const float* ag1  = (const float*)d_in[16];
    const float* abt1 = (const float*)d_in[17];
    const float* aw2  = (const float*)d_in[18];
    const float* ab2  = (const float*)d_in[19];
    const float* ag2  = (const float*)d_in[20];
    const float* abt2 = (const float*)d_in[21];
    float* out = (float*)d_out;

    char* ws = (char*)d_ws;
    int*   idxg   = (int*)ws;                       // 344064 B
    u16*   awp1   = (u16*)(ws + 0x54000);           // 131072 B
    u16*   awp2   = (u16*)(ws + 0x74000);           // 131072 B
    u16*   pwp2   = (u16*)(ws + 0x94000);           // 131072 B
    float* v      = (float*)(ws + 0xC0000);         // 2 MB
    float* asrc   = (float*)(ws + 0x2C0000);        // 2 MB
    float* adst   = (float*)(ws + 0x4C0000);        // 2 MB
    u16*   delta  = (u16*)(ws + 0x6C0000);          // 22020096 B (bf16)
    u16*   alphaF = (u16*)(ws + 0x6C0000 + 0x1500000);  // 22020096 B (bf16)

    k_knn  <<<NN,       64,  0, stream>>>(pos, idxg);
    k_wconv<<<256,      256, 0, stream>>>(aw1, awp1, HD, 2);  // K=128: kpack=4
    k_wconv<<<256,      256, 0, stream>>>(aw2, awp2, CO, 4);  // K=512: kpack=16
    k_wconv<<<256,      256, 0, stream>>>(pw2, pwp2, CO, 4);  // K=512: kpack=16
    k_lin3 <<<NN/8,     256, 0, stream>>>(x, Wl, Wsrc, Wdst, v, asrc, adst);
    k_posnn<<<EDGES/32, 256, 0, stream>>>(pos, idxg, pw1, pb1, pg1, pbt1,
                                          pwp2, pb2, pg2, pbt2, delta);
    k_amlp <<<EDGES/32, 256, 0, stream>>>(idxg, asrc, adst, delta,
                                          awp1, ab1, ag1, abt1,
                                          awp2, ab2, ag2, abt2, alphaF);
    k_agg  <<<NN/8,     256, 0, stream>>>(idxg, v, delta, alphaF, out);
}

// Round 4
// 301.786 us; speedup vs baseline: 4.5957x; 1.1804x over previous
//
#include <hip/hip_runtime.h>
#include <math.h>

#define NN    4096
#define CIN   128
#define CO    128
#define HD    512
#define KK    20
#define EE    21
#define EDGES (NN * EE)   // 86016
#define LNEPS 1e-5f

typedef unsigned short u16;
typedef unsigned int   u32;
typedef unsigned long long u64;
typedef __attribute__((ext_vector_type(8))) short bf16x8;
typedef __attribute__((ext_vector_type(8))) short short8v;
typedef __attribute__((ext_vector_type(4))) float f32x4;

#define MFMA16(a,b,c) __builtin_amdgcn_mfma_f32_16x16x32_bf16(a,b,c,0,0,0)

__device__ __forceinline__ u16 f2b(float x) {
    u32 u = __float_as_uint(x);
    u32 r = u + 0x7fffu + ((u >> 16) & 1u);   // round-to-nearest-even
    return (u16)(r >> 16);
}
__device__ __forceinline__ float b2f(u16 h) {
    return __uint_as_float(((u32)h) << 16);
}

// ---------------- kNN: 1 wave per node ----------------
__global__ __launch_bounds__(64) void k_knn(const float* __restrict__ pos,
                                            int* __restrict__ idxg)
{
    int i = blockIdx.x;
    int lane = threadIdx.x;
    float px = pos[3*i], py = pos[3*i+1], pz = pos[3*i+2];
    float bd[KK]; int bi[KK];
#pragma unroll
    for (int s = 0; s < KK; ++s) { bd[s] = INFINITY; bi[s] = 0x7fffffff; }
    for (int j = lane; j < NN; j += 64) {
        float dx = px - pos[3*j], dy = py - pos[3*j+1], dz = pz - pos[3*j+2];
        float d2 = dx*dx + dy*dy + dz*dz;
        if (j != i && d2 < bd[KK-1]) {
            float cd = d2; int ci = j;
#pragma unroll
            for (int s = 0; s < KK; ++s) {   // static-index bubble insert
                bool sw = cd < bd[s];
                float td = sw ? bd[s] : cd;  int ti = sw ? bi[s] : ci;
                bd[s] = sw ? cd : bd[s];     bi[s] = sw ? ci : bi[s];
                cd = td; ci = ti;
            }
        }
    }
    for (int r = 0; r < KK; ++r) {
        u64 m = ~0ull;
#pragma unroll
        for (int s = 0; s < KK; ++s) {
            u64 k = ((u64)__float_as_uint(bd[s]) << 32) | (u32)bi[s];
            m = k < m ? k : m;
        }
#pragma unroll
        for (int off = 32; off > 0; off >>= 1) {
            u64 o = __shfl_xor(m, off, 64);
            m = o < m ? o : m;
        }
        if (lane == 0) idxg[i*EE + r] = (int)(u32)m;
#pragma unroll
        for (int s = 0; s < KK; ++s) {
            u64 k = ((u64)__float_as_uint(bd[s]) << 32) | (u32)bi[s];
            if (k == m) bd[s] = INFINITY;
        }
    }
    if (lane == 0) idxg[i*EE + KK] = i;   // self-loop appended
}

// ---------------- v / a_src / a_dst ----------------
__global__ __launch_bounds__(256) void k_lin3(const float* __restrict__ x,
        const float* __restrict__ Wl, const float* __restrict__ Ws, const float* __restrict__ Wd,
        float* __restrict__ v, float* __restrict__ as_, float* __restrict__ ad)
{
    __shared__ float sx[8][CIN];
    int b = blockIdx.x, t = threadIdx.x;
    int n0 = b * 8;
    for (int q = t; q < 8*CIN; q += 256) sx[q >> 7][q & 127] = x[n0*CIN + q];
    __syncthreads();
    int c = t & 127, g = t >> 7;
    float al[4] = {0,0,0,0}, asr[4] = {0,0,0,0}, adr[4] = {0,0,0,0};
    for (int k = 0; k < CIN; ++k) {
        float wl = Wl[k*CO + c], ws = Ws[k*CO + c], wd = Wd[k*CO + c];
#pragma unroll
        for (int nn2 = 0; nn2 < 4; ++nn2) {
            float xv = sx[g*4 + nn2][k];
            al[nn2]  = fmaf(xv, wl, al[nn2]);
            asr[nn2] = fmaf(xv, ws, asr[nn2]);
            adr[nn2] = fmaf(xv, wd, adr[nn2]);
        }
    }
#pragma unroll
    for (int nn2 = 0; nn2 < 4; ++nn2) {
        int n = n0 + g*4 + nn2;
        v[n*CO + c]   = al[nn2];
        as_[n*CO + c] = asr[nn2];
        ad[n*CO + c]  = adr[nn2];
    }
}

// ---------------- weight prepack (3-in-1): f32 [K][N] -> bf16 [N/16][K/32][64][8] ----------------
__global__ __launch_bounds__(256) void k_wconv3(
        const float* __restrict__ aw1, const float* __restrict__ aw2,
        const float* __restrict__ pw2,
        u16* __restrict__ awp1, u16* __restrict__ awp2, u16* __restrict__ pwp2)
{
    int gb = blockIdx.x;
    const float* src; u16* dst; int N, kplog, base;
    if (gb < 256)      { src = aw1; dst = awp1; N = HD; kplog = 2; base = 0;   }
    else if (gb < 512) { src = aw2; dst = awp2; N = CO; kplog = 4; base = 256; }
    else               { src = pw2; dst = pwp2; N = CO; kplog = 4; base = 512; }
    int idx = (gb - base)*256 + threadIdx.x;
    int j  = idx & 7;
    int l  = (idx >> 3) & 63;
    int ks = (idx >> 9) & ((1 << kplog) - 1);
    int nt = idx >> (9 + kplog);
    int k = ks*32 + (l >> 4)*8 + j;
    int c = nt*16 + (l & 15);
    dst[idx] = f2b(src[(size_t)k*N + c]);
}

// ---------------- LayerNorm + ELU (bf16 rows in LDS, vectorized) ----------------
template<int L>
__device__ __forceinline__ void ln_elu_b16(u16* base, int rows, int stride,
        const float* __restrict__ gam, const float* __restrict__ bet)
{
    constexpr int P = L / 64;     // contiguous elems per lane
    int t = threadIdx.x, lane = t & 63, w = t >> 6;
    float g[P], b[P];
    if constexpr (P >= 4) {
#pragma unroll
        for (int q = 0; q < P; q += 4) {
            *(float4*)&g[q] = *(const float4*)&gam[lane*P + q];
            *(float4*)&b[q] = *(const float4*)&bet[lane*P + q];
        }
    } else {
        *(float2*)&g[0] = *(const float2*)&gam[lane*P];
        *(float2*)&b[0] = *(const float2*)&bet[lane*P];
    }
    for (int e = w; e < rows; e += 4) {
        u16* row = base + e*stride + lane*P;
        u16 raw[P];
        if constexpr (P == 8) {
            *(ushort4*)&raw[0] = *(const ushort4*)&row[0];
            *(ushort4*)&raw[4] = *(const ushort4*)&row[4];
        } else {
            *(ushort2*)&raw[0] = *(const ushort2*)&row[0];
        }
        float vals[P]; float s = 0.f, sq = 0.f;
#pragma unroll
        for (int q = 0; q < P; ++q) {
            float xx = b2f(raw[q]);
            vals[q] = xx; s += xx; sq += xx*xx;
        }
#pragma unroll
        for (int off = 32; off > 0; off >>= 1) {
            s  += __shfl_xor(s,  off, 64);
            sq += __shfl_xor(sq, off, 64);
        }
        float mn = s * (1.0f / L);
        float rstd = rsqrtf(sq * (1.0f / L) - mn*mn + LNEPS);
#pragma unroll
        for (int q = 0; q < P; ++q) {
            float y = (vals[q] - mn) * rstd * g[q] + b[q];
            y = y > 0.f ? y : __expf(y) - 1.f;   // fast ELU
            raw[q] = f2b(y);
        }
        if constexpr (P == 8) {
            *(ushort4*)&row[0] = *(const ushort4*)&raw[0];
            *(ushort4*)&row[4] = *(const ushort4*)&raw[4];
        } else {
            *(ushort2*)&row[0] = *(const ushort2*)&raw[0];
        }
    }
}

// strides (padded: +8 bf16 keeps ds_read_b128 bank-uniform)
#define SA_S 136
#define SH_S 520

// ---------------- pos_nn: rel -> h(512) -> LN/ELU -> delta(128) -> LN/ELU ----------------
__global__ __launch_bounds__(256, 3) void k_posnn(
        const float* __restrict__ pos, const int* __restrict__ idxg,
        const float* __restrict__ pw1, const float* __restrict__ pb1,
        const float* __restrict__ pg1, const float* __restrict__ pbt1,
        const u16* __restrict__ pwp2, const float* __restrict__ pb2,
        const float* __restrict__ pg2, const float* __restrict__ pbt2,
        u16* __restrict__ delta)
{
    __shared__ __align__(16) u16 s_h[32*SH_S];   // 33280 B
    __shared__ __align__(16) u16 s_d[32*SA_S];   // 8704 B
    __shared__ float s_rel[32][3];
    int t = threadIdx.x;
    int e0g = blockIdx.x * 32;        // 86016 / 32 = 2688 exact
    if (t < 32) {
        int e = e0g + t;
        u32 ii = (u32)e / 21u;
        int j = idxg[e];
        s_rel[t][0] = pos[3*ii]   - pos[3*j];
        s_rel[t][1] = pos[3*ii+1] - pos[3*j+1];
        s_rel[t][2] = pos[3*ii+2] - pos[3*j+2];
    }
    __syncthreads();
    {   // P1: h = rel @ pw1 + pb1 (each thread: 2 channels, all 32 rows)
        int c1 = t, c2 = t + 256;
        float wa0 = pw1[c1], wa1 = pw1[HD + c1], wa2 = pw1[2*HD + c1], ba = pb1[c1];
        float wb0 = pw1[c2], wb1 = pw1[HD + c2], wb2 = pw1[2*HD + c2], bb = pb1[c2];
        for (int r = 0; r < 32; ++r) {
            float r0 = s_rel[r][0], r1 = s_rel[r][1], r2 = s_rel[r][2];
            s_h[r*SH_S + c1] = f2b(ba + r0*wa0 + r1*wa1 + r2*wa2);
            s_h[r*SH_S + c2] = f2b(bb + r0*wb0 + r1*wb1 + r2*wb2);
        }
    }
    __syncthreads();
    ln_elu_b16<HD>(s_h, 32, SH_S, pg1, pbt1);
    __syncthreads();
    {   // P2 (MFMA): delta = h @ pw2 ; [32,512]@[512,128]
        int w = t >> 6, l = t & 63, lr = l & 15, lk = l >> 4;
        int m = w & 1, nt0 = (w >> 1) * 4;
        bf16x8 afr[16];
#pragma unroll
        for (int ks = 0; ks < 16; ++ks)
            afr[ks] = *(const bf16x8*)&s_h[(m*16 + lr)*SH_S + ks*32 + lk*8];
#pragma unroll
        for (int n2 = 0; n2 < 4; ++n2) {
            int nt = nt0 + n2;
            const u16* bp = pwp2 + ((size_t)nt*16*64 + l)*8;
            f32x4 acc = {0.f, 0.f, 0.f, 0.f};
#pragma unroll
            for (int ks = 0; ks < 16; ++ks) {
                bf16x8 bfr = *(const bf16x8*)(bp + ks*512);
                acc = MFMA16(afr[ks], bfr, acc);
            }
            float bias = pb2[nt*16 + lr];
#pragma unroll
            for (int r = 0; r < 4; ++r)
                s_d[(m*16 + lk*4 + r)*SA_S + nt*16 + lr] = f2b(acc[r] + bias);
        }
    }
    __syncthreads();
    ln_elu_b16<CO>(s_d, 32, SA_S, pg2, pbt2);
    __syncthreads();
    {   // vectorized store
        int el = t >> 3, c0 = (t & 7) << 4;
        size_t gb = (size_t)(e0g + el)*CO + c0;
        *(short8v*)&delta[gb]     = *(const short8v*)&s_d[el*SA_S + c0];
        *(short8v*)&delta[gb + 8] = *(const short8v*)&s_d[el*SA_S + c0 + 8];
    }
}

// ---------------- attn MLP (edge-tiled, MFMA) ----------------
__global__ __launch_bounds__(256, 3) void k_amlp(
        const int* __restrict__ idxg,
        const float* __restrict__ as_, const float* __restrict__ ad,
        const u16* __restrict__ delta,
        const u16* __restrict__ awp1, const float* __restrict__ ab1,
        const float* __restrict__ ag1, const float* __restrict__ abt1,
        const u16* __restrict__ awp2, const float* __restrict__ ab2,
        const float* __restrict__ ag2, const float* __restrict__ abt2,
        u16* __restrict__ alphaF)
{
    __shared__ __align__(16) u16 s_a[32*SA_S];   // 8704 B
    __shared__ __align__(16) u16 s_h[32*SH_S];   // 33280 B
    __shared__ __align__(16) u16 s_af[32*SA_S];  // 8704 B
    int t = threadIdx.x;
    int e0g = blockIdx.x * 32;
    {   // alpha0 = a_dst[i] - a_src[j] + delta  (1 row per 8 threads, vectorized)
        int el = t >> 3, c0 = (t & 7) << 4;
        int e = e0g + el;
        int i = (int)((u32)e / 21u);
        int j = idxg[e];
        const float* adp = ad  + i*CIN + c0;
        const float* asp = as_ + j*CIN + c0;
        const u16*  dp   = delta + (size_t)e*CO + c0;
        u16* op = &s_a[el*SA_S + c0];
#pragma unroll
        for (int q = 0; q < 16; q += 8) {
            float4 a0 = *(const float4*)(adp + q);
            float4 a1 = *(const float4*)(adp + q + 4);
            float4 s0 = *(const float4*)(asp + q);
            float4 s1 = *(const float4*)(asp + q + 4);
            short8v d8 = *(const short8v*)(dp + q);
            short8v o;
            o[0] = (short)f2b(a0.x - s0.x + b2f((u16)d8[0]));
            o[1] = (short)f2b(a0.y - s0.y + b2f((u16)d8[1]));
            o[2] = (short)f2b(a0.z - s0.z + b2f((u16)d8[2]));
            o[3] = (short)f2b(a0.w - s0.w + b2f((u16)d8[3]));
            o[4] = (short)f2b(a1.x - s1.x + b2f((u16)d8[4]));
            o[5] = (short)f2b(a1.y - s1.y + b2f((u16)d8[5]));
            o[6] = (short)f2b(a1.z - s1.z + b2f((u16)d8[6]));
            o[7] = (short)f2b(a1.w - s1.w + b2f((u16)d8[7]));
            *(short8v*)(op + q) = o;
        }
    }
    __syncthreads();
    int w = t >> 6, l = t & 63, lr = l & 15, lk = l >> 4;
    {   // A1 (MFMA): h = alpha0 @ aw1 ; [32,128]@[128,512]
        int m = w & 1, nt0 = (w >> 1) * 16;
        bf16x8 afr[4];
#pragma unroll
        for (int ks = 0; ks < 4; ++ks)
            afr[ks] = *(const bf16x8*)&s_a[(m*16 + lr)*SA_S + ks*32 + lk*8];
#pragma unroll
        for (int n2 = 0; n2 < 16; ++n2) {
            int nt = nt0 + n2;
            const u16* bp = awp1 + ((size_t)nt*4*64 + l)*8;
            f32x4 acc = {0.f, 0.f, 0.f, 0.f};
#pragma unroll
            for (int ks = 0; ks < 4; ++ks) {
                bf16x8 bfr = *(const bf16x8*)(bp + ks*512);
                acc = MFMA16(afr[ks], bfr, acc);
            }
            float bias = ab1[nt*16 + lr];
#pragma unroll
            for (int r = 0; r < 4; ++r)
                s_h[(m*16 + lk*4 + r)*SH_S + nt*16 + lr] = f2b(acc[r] + bias);
        }
    }
    __syncthreads();
    ln_elu_b16<HD>(s_h, 32, SH_S, ag1, abt1);
    __syncthreads();
    {   // A2 (MFMA): alphaF = h @ aw2 ; [32,512]@[512,128]
        int m = w & 1, nt0 = (w >> 1) * 4;
        bf16x8 afr[16];
#pragma unroll
        for (int ks = 0; ks < 16; ++ks)
            afr[ks] = *(const bf16x8*)&s_h[(m*16 + lr)*SH_S + ks*32 + lk*8];
#pragma unroll
        for (int n2 = 0; n2 < 4; ++n2) {
            int nt = nt0 + n2;
            const u16* bp = awp2 + ((size_t)nt*16*64 + l)*8;
            f32x4 acc = {0.f, 0.f, 0.f, 0.f};
#pragma unroll
            for (int ks = 0; ks < 16; ++ks) {
                bf16x8 bfr = *(const bf16x8*)(bp + ks*512);
                acc = MFMA16(afr[ks], bfr, acc);
            }
            float bias = ab2[nt*16 + lr];
#pragma unroll
            for (int r = 0; r < 4; ++r)
                s_af[(m*16 + lk*4 + r)*SA_S + nt*16 + lr] = f2b(acc[r] + bias);
        }
    }
    __syncthreads();
    ln_elu_b16<CO>(s_af, 32, SA_S, ag2, abt2);
    __syncthreads();
    {   // vectorized store
        int el = t >> 3, c0 = (t & 7) << 4;
        size_t gb = (size_t)(e0g + el)*CO + c0;
        *(short8v*)&alphaF[gb]     = *(const short8v*)&s_af[el*SA_S + c0];
        *(short8v*)&alphaF[gb + 8] = *(const short8v*)&s_af[el*SA_S + c0 + 8];
    }
}

// ---------------- softmax over neighbors + weighted aggregate ----------------
__global__ __launch_bounds__(256) void k_agg(
        const int* __restrict__ idxg,
        const float* __restrict__ v, const u16* __restrict__ delta,
        const u16* __restrict__ alphaF, float* __restrict__ out)
{
    __shared__ int s_idx[8][EE];
    int b = blockIdx.x, t = threadIdx.x;
    int n0 = b * 8;
    for (int q = t; q < 8*EE; q += 256) s_idx[q/EE][q%EE] = idxg[n0*EE + q];
    __syncthreads();
    int c = t & 127, g = t >> 7;
    for (int ng = g; ng < 8; ng += 2) {
        int i = n0 + ng;
        size_t base = (size_t)i*EE*CO + c;
        float af[EE]; float mx = -INFINITY;
#pragma unroll
        for (int e = 0; e < EE; ++e) { af[e] = b2f(alphaF[base + e*CO]); mx = fmaxf(mx, af[e]); }
        float ssum = 0.f;
#pragma unroll
        for (int e = 0; e < EE; ++e) { af[e] = __expf(af[e] - mx); ssum += af[e]; }
        float accv = 0.f;
#pragma unroll
        for (int e = 0; e < EE; ++e) {
            int j = s_idx[ng][e];
            float msg = v[j*CO + c] + b2f(delta[base + e*CO]);
            accv = fmaf(af[e], msg, accv);
        }
        out[i*CO + c] = accv / ssum;
    }
}

extern "C" void kernel_launch(void* const* d_in, const int* in_sizes, int n_in,
                              void* d_out, int out_size, void* d_ws, size_t ws_size,
                              hipStream_t stream)
{
    const float* x    = (const float*)d_in[0];
    const float* pos  = (const float*)d_in[1];
    const float* Wl   = (const float*)d_in[3];
    const float* Wsrc = (const float*)d_in[4];
    const float* Wdst = (const float*)d_in[5];
    const float* pw1  = (const float*)d_in[6];
    const float* pb1  = (const float*)d_in[7];
    const float* pg1  = (const float*)d_in[8];
    const float* pbt1 = (const float*)d_in[9];
    const float* pw2  = (const float*)d_in[10];
    const float* pb2  = (const float*)d_in[11];
    const float* pg2  = (const float*)d_in[12];
    const float* pbt2 = (const float*)d_in[13];
    const float* aw1  = (const float*)d_in[14];
    const float* ab1  = (const float*)d_in[15];
    const float* ag1  = (const float*)d_in[16];
    const float* abt1 = (const float*)d_in[17];
    const float* aw2  = (const float*)d_in[18];
    const float* ab2  = (const float*)d_in[19];
    const float* ag2  = (const float*)d_in[20];
    const float* abt2 = (const float*)d_in[21];
    float* out = (float*)d_out;

    char* ws = (char*)d_ws;
    int*   idxg   = (int*)ws;                       // 344064 B
    u16*   awp1   = (u16*)(ws + 0x54000);           // 131072 B
    u16*   awp2   = (u16*)(ws + 0x74000);           // 131072 B
    u16*   pwp2   = (u16*)(ws + 0x94000);           // 131072 B
    float* v      = (float*)(ws + 0xC0000);         // 2 MB
    float* asrc   = (float*)(ws + 0x2C0000);        // 2 MB
    float* adst   = (float*)(ws + 0x4C0000);        // 2 MB
    u16*   delta  = (u16*)(ws + 0x6C0000);          // 22020096 B (bf16)
    u16*   alphaF = (u16*)(ws + 0x6C0000 + 0x1500000);  // 22020096 B (bf16)

    k_knn   <<<NN,       64,  0, stream>>>(pos, idxg);
    k_wconv3<<<768,      256, 0, stream>>>(aw1, aw2, pw2, awp1, awp2, pwp2);
    k_lin3  <<<NN/8,     256, 0, stream>>>(x, Wl, Wsrc, Wdst, v, asrc, adst);
    k_posnn <<<EDGES/32, 256, 0, stream>>>(pos, idxg, pw1, pb1, pg1, pbt1,
                                           pwp2, pb2, pg2, pbt2, delta);
    k_amlp  <<<EDGES/32, 256, 0, stream>>>(idxg, asrc, adst, delta,
                                           awp1, ab1, ag1, abt1,
                                           awp2, ab2, ag2, abt2, alphaF);
    k_agg   <<<NN/8,     256, 0, stream>>>(idxg, v, delta, alphaF, out);
}

// Round 9
// 291.982 us; speedup vs baseline: 4.7500x; 1.0336x over previous
//
#include <hip/hip_runtime.h>
#include <math.h>

#define NN    4096
#define CIN   128
#define CO    128
#define HD    512
#define KK    20
#define EE    21
#define EDGES (NN * EE)   // 86016
#define LNEPS 1e-5f

typedef unsigned short u16;
typedef unsigned int   u32;
typedef unsigned long long u64;
typedef __attribute__((ext_vector_type(8))) short bf16x8;
typedef __attribute__((ext_vector_type(4))) float f32x4;

#define MFMA16(a,b,c) __builtin_amdgcn_mfma_f32_16x16x32_bf16(a,b,c,0,0,0)

__device__ __forceinline__ u16 f2b(float x) {
    u32 u = __float_as_uint(x);
    u32 r = u + 0x7fffu + ((u >> 16) & 1u);   // round-to-nearest-even
    return (u16)(r >> 16);
}
__device__ __forceinline__ float b2f(u16 h) {
    return __uint_as_float(((u32)h) << 16);
}

// ---------------- kNN: 1 wave per node ----------------
__global__ __launch_bounds__(64) void k_knn(const float* __restrict__ pos,
                                            int* __restrict__ idxg)
{
    int i = blockIdx.x;
    int lane = threadIdx.x;
    float px = pos[3*i], py = pos[3*i+1], pz = pos[3*i+2];
    float bd[KK]; int bi[KK];
#pragma unroll
    for (int s = 0; s < KK; ++s) { bd[s] = INFINITY; bi[s] = 0x7fffffff; }
    for (int j = lane; j < NN; j += 64) {
        float dx = px - pos[3*j], dy = py - pos[3*j+1], dz = pz - pos[3*j+2];
        float d2 = dx*dx + dy*dy + dz*dz;
        if (j != i && d2 < bd[KK-1]) {
            float cd = d2; int ci = j;
#pragma unroll
            for (int s = 0; s < KK; ++s) {   // static-index bubble insert
                bool sw = cd < bd[s];
                float td = sw ? bd[s] : cd;  int ti = sw ? bi[s] : ci;
                bd[s] = sw ? cd : bd[s];     bi[s] = sw ? ci : bi[s];
                cd = td; ci = ti;
            }
        }
    }
    for (int r = 0; r < KK; ++r) {
        u64 m = ~0ull;
#pragma unroll
        for (int s = 0; s < KK; ++s) {
            u64 k = ((u64)__float_as_uint(bd[s]) << 32) | (u32)bi[s];
            m = k < m ? k : m;
        }
#pragma unroll
        for (int off = 32; off > 0; off >>= 1) {
            u64 o = __shfl_xor(m, off, 64);
            m = o < m ? o : m;
        }
        if (lane == 0) idxg[i*EE + r] = (int)(u32)m;
#pragma unroll
        for (int s = 0; s < KK; ++s) {
            u64 k = ((u64)__float_as_uint(bd[s]) << 32) | (u32)bi[s];
            if (k == m) bd[s] = INFINITY;
        }
    }
    if (lane == 0) idxg[i*EE + KK] = i;   // self-loop appended
}

// ---------------- v / a_src / a_dst ----------------
__global__ __launch_bounds__(256) void k_lin3(const float* __restrict__ x,
        const float* __restrict__ Wl, const float* __restrict__ Ws, const float* __restrict__ Wd,
        float* __restrict__ v, float* __restrict__ as_, float* __restrict__ ad)
{
    __shared__ float sx[8][CIN];
    int b = blockIdx.x, t = threadIdx.x;
    int n0 = b * 8;
    for (int q = t; q < 8*CIN; q += 256) sx[q >> 7][q & 127] = x[n0*CIN + q];
    __syncthreads();
    int c = t & 127, g = t >> 7;
    float al[4] = {0,0,0,0}, asr[4] = {0,0,0,0}, adr[4] = {0,0,0,0};
    for (int k = 0; k < CIN; ++k) {
        float wl = Wl[k*CO + c], ws = Ws[k*CO + c], wd = Wd[k*CO + c];
#pragma unroll
        for (int nn2 = 0; nn2 < 4; ++nn2) {
            float xv = sx[g*4 + nn2][k];
            al[nn2]  = fmaf(xv, wl, al[nn2]);
            asr[nn2] = fmaf(xv, ws, asr[nn2]);
            adr[nn2] = fmaf(xv, wd, adr[nn2]);
        }
    }
#pragma unroll
    for (int nn2 = 0; nn2 < 4; ++nn2) {
        int n = n0 + g*4 + nn2;
        v[n*CO + c]   = al[nn2];
        as_[n*CO + c] = asr[nn2];
        ad[n*CO + c]  = adr[nn2];
    }
}

// ---------------- weight prepack (3-in-1): f32 [K][N] -> bf16 [N/16][K/32][64][8] ----------------
__global__ __launch_bounds__(256) void k_wconv3(
        const float* __restrict__ aw1, const float* __restrict__ aw2,
        const float* __restrict__ pw2,
        u16* __restrict__ awp1, u16* __restrict__ awp2, u16* __restrict__ pwp2)
{
    int gb = blockIdx.x;
    const float* src; u16* dst; int N, kplog, base;
    if (gb < 256)      { src = aw1; dst = awp1; N = HD; kplog = 2; base = 0;   }
    else if (gb < 512) { src = aw2; dst = awp2; N = CO; kplog = 4; base = 256; }
    else               { src = pw2; dst = pwp2; N = CO; kplog = 4; base = 512; }
    int idx = (gb - base)*256 + threadIdx.x;
    int j  = idx & 7;
    int l  = (idx >> 3) & 63;
    int ks = (idx >> 9) & ((1 << kplog) - 1);
    int nt = idx >> (9 + kplog);
    int k = ks*32 + (l >> 4)*8 + j;
    int c = nt*16 + (l & 15);
    dst[idx] = f2b(src[(size_t)k*N + c]);
}

// ---------------- LayerNorm + ELU on bf16 rows (L=512), NW waves ----------------
template<int L, int NW>
__device__ __forceinline__ void ln_elu_b16(u16* base, int rows, int stride,
        const float* __restrict__ gam, const float* __restrict__ bet)
{
    constexpr int P = L / 64;     // contiguous elems per lane
    int t = threadIdx.x, lane = t & 63, w = t >> 6;
    float g[P], b[P];
#pragma unroll
    for (int q = 0; q < P; q += 4) {
        *(float4*)&g[q] = *(const float4*)&gam[lane*P + q];
        *(float4*)&b[q] = *(const float4*)&bet[lane*P + q];
    }
    for (int e = w; e < rows; e += NW) {
        u16* row = base + e*stride + lane*P;
        u16 raw[P];
        *(ushort4*)&raw[0] = *(const ushort4*)&row[0];
        *(ushort4*)&raw[4] = *(const ushort4*)&row[4];
        float vals[P]; float s = 0.f, sq = 0.f;
#pragma unroll
        for (int q = 0; q < P; ++q) {
            float xx = b2f(raw[q]);
            vals[q] = xx; s += xx; sq += xx*xx;
        }
#pragma unroll
        for (int off = 32; off > 0; off >>= 1) {
            s  += __shfl_xor(s,  off, 64);
            sq += __shfl_xor(sq, off, 64);
        }
        float mn = s * (1.0f / L);
        float rstd = rsqrtf(sq * (1.0f / L) - mn*mn + LNEPS);
#pragma unroll
        for (int q = 0; q < P; ++q) {
            float y = (vals[q] - mn) * rstd * g[q] + b[q];
            y = y > 0.f ? y : __expf(y) - 1.f;   // fast ELU
            raw[q] = f2b(y);
        }
        *(ushort4*)&row[0] = *(const ushort4*)&raw[0];
        *(ushort4*)&row[4] = *(const ushort4*)&raw[4];
    }
}

// ---------------- LayerNorm + ELU on f32 rows (L=128), NW waves ----------------
template<int L, int NW>
__device__ __forceinline__ void ln_elu_f32v(float* base, int rows, int stride,
        const float* __restrict__ gam, const float* __restrict__ bet)
{
    constexpr int P = L / 64;     // 2
    int t = threadIdx.x, lane = t & 63, w = t >> 6;
    float g[P], b[P];
    *(float2*)&g[0] = *(const float2*)&gam[lane*P];
    *(float2*)&b[0] = *(const float2*)&bet[lane*P];
    for (int e = w; e < rows; e += NW) {
        float* row = base + e*stride + lane*P;
        float vals[P];
        *(float2*)&vals[0] = *(const float2*)&row[0];
        float s = 0.f, sq = 0.f;
#pragma unroll
        for (int q = 0; q < P; ++q) { s += vals[q]; sq += vals[q]*vals[q]; }
#pragma unroll
        for (int off = 32; off > 0; off >>= 1) {
            s  += __shfl_xor(s,  off, 64);
            sq += __shfl_xor(sq, off, 64);
        }
        float mn = s * (1.0f / L);
        float rstd = rsqrtf(sq * (1.0f / L) - mn*mn + LNEPS);
#pragma unroll
        for (int q = 0; q < P; ++q) {
            float y = (vals[q] - mn) * rstd * g[q] + b[q];
            vals[q] = y > 0.f ? y : __expf(y) - 1.f;
        }
        *(float2*)&row[0] = *(const float2*)&vals[0];
    }
}

// strides (padded)
#define SA_S 136   // u16, 128+8
#define SH_S 520   // u16, 512+8
#define SF_S 132   // f32, 128+4

// ---------------- pos_nn (8 waves, f32 final-LN staging) ----------------
__global__ __launch_bounds__(512) void k_posnn(
        const float* __restrict__ pos, const int* __restrict__ idxg,
        const float* __restrict__ pw1, const float* __restrict__ pb1,
        const float* __restrict__ pg1, const float* __restrict__ pbt1,
        const u16* __restrict__ pwp2, const float* __restrict__ pb2,
        const float* __restrict__ pg2, const float* __restrict__ pbt2,
        u16* __restrict__ delta)
{
    __shared__ __align__(16) u16   s_h[32*SH_S];   // 33280 B
    __shared__ __align__(16) float s_d[32*SF_S];   // 16896 B
    __shared__ float s_rel[32][3];
    int t = threadIdx.x;
    int e0g = blockIdx.x * 32;        // 86016 / 32 = 2688 exact
    if (t < 32) {
        int e = e0g + t;
        u32 ii = (u32)e / 21u;
        int j = idxg[e];
        s_rel[t][0] = pos[3*ii]   - pos[3*j];
        s_rel[t][1] = pos[3*ii+1] - pos[3*j+1];
        s_rel[t][2] = pos[3*ii+2] - pos[3*j+2];
    }
    __syncthreads();
    {   // P1: h = rel @ pw1 + pb1 (pinned fmaf chain; 1 channel/thread)
        int c1 = t;
        float wa0 = pw1[c1], wa1 = pw1[HD + c1], wa2 = pw1[2*HD + c1], ba = pb1[c1];
        for (int r = 0; r < 32; ++r) {
            float hv = fmaf(s_rel[r][2], wa2, fmaf(s_rel[r][1], wa1, fmaf(s_rel[r][0], wa0, ba)));
            s_h[r*SH_S + c1] = f2b(hv);
        }
    }
    __syncthreads();
    ln_elu_b16<HD, 8>(s_h, 32, SH_S, pg1, pbt1);
    __syncthreads();
    {   // P2 (MFMA): [32,512]@[512,128]; 8 waves x 2 n-tiles
        int w = t >> 6, l = t & 63, lr = l & 15, lk = l >> 4;
        int m = w & 1, nt0 = (w >> 1) * 2;
        bf16x8 afr[16];
#pragma unroll
        for (int ks = 0; ks < 16; ++ks)
            afr[ks] = *(const bf16x8*)&s_h[(m*16 + lr)*SH_S + ks*32 + lk*8];
#pragma unroll
        for (int n2 = 0; n2 < 2; ++n2) {
            int nt = nt0 + n2;
            const u16* bp = pwp2 + ((size_t)nt*16*64 + l)*8;
            f32x4 acc = {0.f, 0.f, 0.f, 0.f};
#pragma unroll
            for (int ks = 0; ks < 16; ++ks) {
                bf16x8 bfr = *(const bf16x8*)(bp + ks*512);
                acc = MFMA16(afr[ks], bfr, acc);
            }
            float bias = pb2[nt*16 + lr];
#pragma unroll
            for (int r = 0; r < 4; ++r)
                s_d[(m*16 + lk*4 + r)*SF_S + nt*16 + lr] = acc[r] + bias;
        }
    }
    __syncthreads();
    ln_elu_f32v<CO, 8>(s_d, 32, SF_S, pg2, pbt2);
    __syncthreads();
    {   // store: 16 threads/row, 8 cols each; f2b at the end only
        int el = t >> 4, c0 = (t & 15) << 3;
        const float* sp = &s_d[el*SF_S + c0];
        float4 v0 = *(const float4*)(sp);
        float4 v1 = *(const float4*)(sp + 4);
        bf16x8 o;
        o[0] = (short)f2b(v0.x); o[1] = (short)f2b(v0.y);
        o[2] = (short)f2b(v0.z); o[3] = (short)f2b(v0.w);
        o[4] = (short)f2b(v1.x); o[5] = (short)f2b(v1.y);
        o[6] = (short)f2b(v1.z); o[7] = (short)f2b(v1.w);
        *(bf16x8*)&delta[(size_t)(e0g + el)*CO + c0] = o;
    }
}

// ---------------- attn MLP (8 waves, f32 final-LN staging) ----------------
__global__ __launch_bounds__(512) void k_amlp(
        const int* __restrict__ idxg,
        const float* __restrict__ as_, const float* __restrict__ ad,
        const u16* __restrict__ delta,
        const u16* __restrict__ awp1, const float* __restrict__ ab1,
        const float* __restrict__ ag1, const float* __restrict__ abt1,
        const u16* __restrict__ awp2, const float* __restrict__ ab2,
        const float* __restrict__ ag2, const float* __restrict__ abt2,
        u16* __restrict__ alphaF)
{
    __shared__ __align__(16) u16   s_a[32*SA_S];   // 8704 B
    __shared__ __align__(16) u16   s_h[32*SH_S];   // 33280 B
    __shared__ __align__(16) float s_af[32*SF_S];  // 16896 B
    int t = threadIdx.x;
    int e0g = blockIdx.x * 32;
    {   // alpha0 = a_dst[i] - a_src[j] + delta  (16 threads/row, 8 cols each)
        int el = t >> 4, c0 = (t & 15) << 3;
        int e = e0g + el;
        int i = (int)((u32)e / 21u);
        int j = idxg[e];
        const float* adp = ad  + i*CIN + c0;
        const float* asp = as_ + j*CIN + c0;
        const u16*  dp   = delta + (size_t)e*CO + c0;
        float4 a0 = *(const float4*)(adp);
        float4 a1 = *(const float4*)(adp + 4);
        float4 s0 = *(const float4*)(asp);
        float4 s1 = *(const float4*)(asp + 4);
        bf16x8 d8 = *(const bf16x8*)(dp);
        bf16x8 o;
        o[0] = (short)f2b(a0.x - s0.x + b2f((u16)d8[0]));
        o[1] = (short)f2b(a0.y - s0.y + b2f((u16)d8[1]));
        o[2] = (short)f2b(a0.z - s0.z + b2f((u16)d8[2]));
        o[3] = (short)f2b(a0.w - s0.w + b2f((u16)d8[3]));
        o[4] = (short)f2b(a1.x - s1.x + b2f((u16)d8[4]));
        o[5] = (short)f2b(a1.y - s1.y + b2f((u16)d8[5]));
        o[6] = (short)f2b(a1.z - s1.z + b2f((u16)d8[6]));
        o[7] = (short)f2b(a1.w - s1.w + b2f((u16)d8[7]));
        *(bf16x8*)&s_a[el*SA_S + c0] = o;
    }
    __syncthreads();
    int w = t >> 6, l = t & 63, lr = l & 15, lk = l >> 4;
    {   // A1 (MFMA): [32,128]@[128,512]; 8 waves x 8 n-tiles
        int m = w & 1, nt0 = (w >> 1) * 8;
        bf16x8 afr[4];
#pragma unroll
        for (int ks = 0; ks < 4; ++ks)
            afr[ks] = *(const bf16x8*)&s_a[(m*16 + lr)*SA_S + ks*32 + lk*8];
#pragma unroll
        for (int n2 = 0; n2 < 8; ++n2) {
            int nt = nt0 + n2;
            const u16* bp = awp1 + ((size_t)nt*4*64 + l)*8;
            f32x4 acc = {0.f, 0.f, 0.f, 0.f};
#pragma unroll
            for (int ks = 0; ks < 4; ++ks) {
                bf16x8 bfr = *(const bf16x8*)(bp + ks*512);
                acc = MFMA16(afr[ks], bfr, acc);
            }
            float bias = ab1[nt*16 + lr];
#pragma unroll
            for (int r = 0; r < 4; ++r)
                s_h[(m*16 + lk*4 + r)*SH_S + nt*16 + lr] = f2b(acc[r] + bias);
        }
    }
    __syncthreads();
    ln_elu_b16<HD, 8>(s_h, 32, SH_S, ag1, abt1);
    __syncthreads();
    {   // A2 (MFMA): [32,512]@[512,128]; 8 waves x 2 n-tiles
        int m = w & 1, nt0 = (w >> 1) * 2;
        bf16x8 afr[16];
#pragma unroll
        for (int ks = 0; ks < 16; ++ks)
            afr[ks] = *(const bf16x8*)&s_h[(m*16 + lr)*SH_S + ks*32 + lk*8];
#pragma unroll
        for (int n2 = 0; n2 < 2; ++n2) {
            int nt = nt0 + n2;
            const u16* bp = awp2 + ((size_t)nt*16*64 + l)*8;
            f32x4 acc = {0.f, 0.f, 0.f, 0.f};
#pragma unroll
            for (int ks = 0; ks < 16; ++ks) {
                bf16x8 bfr = *(const bf16x8*)(bp + ks*512);
                acc = MFMA16(afr[ks], bfr, acc);
            }
            float bias = ab2[nt*16 + lr];
#pragma unroll
            for (int r = 0; r < 4; ++r)
                s_af[(m*16 + lk*4 + r)*SF_S + nt*16 + lr] = acc[r] + bias;
        }
    }
    __syncthreads();
    ln_elu_f32v<CO, 8>(s_af, 32, SF_S, ag2, abt2);
    __syncthreads();
    {   // store: f2b at the end only
        int el = t >> 4, c0 = (t & 15) << 3;
        const float* sp = &s_af[el*SF_S + c0];
        float4 v0 = *(const float4*)(sp);
        float4 v1 = *(const float4*)(sp + 4);
        bf16x8 o;
        o[0] = (short)f2b(v0.x); o[1] = (short)f2b(v0.y);
        o[2] = (short)f2b(v0.z); o[3] = (short)f2b(v0.w);
        o[4] = (short)f2b(v1.x); o[5] = (short)f2b(v1.y);
        o[6] = (short)f2b(v1.z); o[7] = (short)f2b(v1.w);
        *(bf16x8*)&alphaF[(size_t)(e0g + el)*CO + c0] = o;
    }
}

// ---------------- softmax over neighbors + weighted aggregate ----------------
__global__ __launch_bounds__(256) void k_agg(
        const int* __restrict__ idxg,
        const float* __restrict__ v, const u16* __restrict__ delta,
        const u16* __restrict__ alphaF, float* __restrict__ out)
{
    __shared__ int s_idx[8][EE];
    int b = blockIdx.x, t = threadIdx.x;
    int n0 = b * 8;
    for (int q = t; q < 8*EE; q += 256) s_idx[q/EE][q%EE] = idxg[n0*EE + q];
    __syncthreads();
    int c = t & 127, g = t >> 7;
    for (int ng = g; ng < 8; ng += 2) {
        int i = n0 + ng;
        size_t base = (size_t)i*EE*CO + c;
        float af[EE]; float mx = -INFINITY;
#pragma unroll
        for (int e = 0; e < EE; ++e) { af[e] = b2f(alphaF[base + e*CO]); mx = fmaxf(mx, af[e]); }
        float ssum = 0.f;
#pragma unroll
        for (int e = 0; e < EE; ++e) { af[e] = __expf(af[e] - mx); ssum += af[e]; }
        float accv = 0.f;
#pragma unroll
        for (int e = 0; e < EE; ++e) {
            int j = s_idx[ng][e];
            float msg = v[j*CO + c] + b2f(delta[base + e*CO]);
            accv = fmaf(af[e], msg, accv);
        }
        out[i*CO + c] = accv / ssum;
    }
}

extern "C" void kernel_launch(void* const* d_in, const int* in_sizes, int n_in,
                              void* d_out, int out_size, void* d_ws, size_t ws_size,
                              hipStream_t stream)
{
    const float* x    = (const float*)d_in[0];
    const float* pos  = (const float*)d_in[1];
    const float* Wl   = (const float*)d_in[3];
    const float* Wsrc = (const float*)d_in[4];
    const float* Wdst = (const float*)d_in[5];
    const float* pw1  = (const float*)d_in[6];
    const float* pb1  = (const float*)d_in[7];
    const float* pg1  = (const float*)d_in[8];
    const float* pbt1 = (const float*)d_in[9];
    const float* pw2  = (const float*)d_in[10];
    const float* pb2  = (const float*)d_in[11];
    const float* pg2  = (const float*)d_in[12];
    const float* pbt2 = (const float*)d_in[13];
    const float* aw1  = (const float*)d_in[14];
    const float* ab1  = (const float*)d_in[15];
    const float* ag1  = (const float*)d_in[16];
    const float* abt1 = (const float*)d_in[17];
    const float* aw2  = (const float*)d_in[18];
    const float* ab2  = (const float*)d_in[19];
    const float* ag2  = (const float*)d_in[20];
    const float* abt2 = (const float*)d_in[21];
    float* out = (float*)d_out;

    char* ws = (char*)d_ws;
    int*   idxg   = (int*)ws;                       // 344064 B
    u16*   awp1   = (u16*)(ws + 0x54000);           // 131072 B
    u16*   awp2   = (u16*)(ws + 0x74000);           // 131072 B
    u16*   pwp2   = (u16*)(ws + 0x94000);           // 131072 B
    float* v      = (float*)(ws + 0xC0000);         // 2 MB
    float* asrc   = (float*)(ws + 0x2C0000);        // 2 MB
    float* adst   = (float*)(ws + 0x4C0000);        // 2 MB
    u16*   delta  = (u16*)(ws + 0x6C0000);          // 22020096 B (bf16)
    u16*   alphaF = (u16*)(ws + 0x6C0000 + 0x1500000);  // 22020096 B (bf16)

    k_knn   <<<NN,       64,  0, stream>>>(pos, idxg);
    k_wconv3<<<768,      256, 0, stream>>>(aw1, aw2, pw2, awp1, awp2, pwp2);
    k_lin3  <<<NN/8,     256, 0, stream>>>(x, Wl, Wsrc, Wdst, v, asrc, adst);
    k_posnn <<<EDGES/32, 512, 0, stream>>>(pos, idxg, pw1, pb1, pg1, pbt1,
                                           pwp2, pb2, pg2, pbt2, delta);
    k_amlp  <<<EDGES/32, 512, 0, stream>>>(idxg, asrc, adst, delta,
                                           awp1, ab1, ag1, abt1,
                                           awp2, ab2, ag2, abt2, alphaF);
    k_agg   <<<NN/8,     256, 0, stream>>>(idxg, v, delta, alphaF, out);
}